// Round 1
// baseline (308.844 us; speedup 1.0000x reference)
//
#include <hip/hip_runtime.h>

// MultiHeadAttention forward, MI355X gfx950.
// B=128, T=256, C=384, H=6, hs=64. All GEMM-shaped work in bf16 MFMA
// (mfma_f32_16x16x32_bf16), f32 accumulate. Threshold is ~2% (bf16-class).
//
// Pipeline:
//   1) qkv_kernel : q = x@Wq, k = x@Wk, v = x@Wv  -> ws (bf16)
//        q_ws, k_ws laid out [B,H,T,64]; v stored TRANSPOSED [B,H,64,T]
//   2) attn_kernel: per (qtile, b*h): S = Q K^T * scale, causal softmax
//        in-register, P(normalized, bf16) -> LDS, O = P V via MFMA,
//        written to o_ws as [B*T, 384] bf16 (row-major, heads interleaved)
//   3) proj_kernel: out = O @ Wp + bp  (f32 out)
//
// ws usage: 4 * 32768*384 * 2B = 100,663,296 bytes.

#define T_SEQ 256
#define NH 6
#define HS 64
#define CIN 384
#define BATCH 128
#define BT (BATCH * T_SEQ)            // 32768
#define ELEMS ((size_t)BT * CIN)      // 12,582,912 per buffer

using f32x4  = __attribute__((ext_vector_type(4))) float;
using bf16x8 = __attribute__((ext_vector_type(8))) short;  // 8 bf16 in 4 VGPRs

// f32 -> bf16 round-to-nearest-even
static __device__ __forceinline__ unsigned short f2bf(float f) {
  union { float f; unsigned u; } v; v.f = f;
  unsigned r = v.u + 0x7FFFu + ((v.u >> 16) & 1u);
  return (unsigned short)(r >> 16);
}

static __device__ __forceinline__ bf16x8 ld_bf8(const unsigned short* p) {
  return *reinterpret_cast<const bf16x8*>(p);
}

// ---------------------------------------------------------------------------
// Kernel 1: QKV projection. Tile 64(M) x 64(N), 4 waves, each wave owns a
// 16x64 strip (4 MFMA n-tiles). K loop in steps of 32.
// blockIdx.z selects weight: 0->Wq->q_ws, 1->Wk->k_ws, 2->Wv->vT_ws.
// MFMA layouts (verified, learn_hip m89/m91):
//   A: lane l holds A[l&15][8*(l>>4)+j]   (8 contiguous k)
//   B: lane l holds B[8*(l>>4)+j][l&15]   (8 contiguous k of one column)
//   D: lane l holds D[4*(l>>4)+i][l&15]
// ---------------------------------------------------------------------------
__global__ __launch_bounds__(256) void qkv_kernel(
    const float* __restrict__ x,
    const float* __restrict__ Wq, const float* __restrict__ Wk,
    const float* __restrict__ Wv,
    unsigned short* __restrict__ q_ws, unsigned short* __restrict__ k_ws,
    unsigned short* __restrict__ vT_ws)
{
  __shared__ __align__(16) unsigned short XA[64][32];  // [m][k] bf16
  __shared__ __align__(16) unsigned short WT[64][32];  // [n][k] bf16 (transposed)

  const int tid = threadIdx.x;
  const int w = tid >> 6, l = tid & 63, g = l >> 4, c = l & 15;
  const int m0 = blockIdx.x * 64;
  const int n0 = blockIdx.y * 64;
  const int z  = blockIdx.z;
  const float* __restrict__ W = (z == 0) ? Wq : (z == 1) ? Wk : Wv;

  f32x4 acc[4];
#pragma unroll
  for (int nt = 0; nt < 4; ++nt) { f32x4 zz = {0.f, 0.f, 0.f, 0.f}; acc[nt] = zz; }

  const int rX = tid >> 2, cpX = (tid & 3) * 8;   // X stage: 8 f32 per thread
  const int kW = tid >> 3, npW = (tid & 7) * 8;   // W stage: 8 f32 per thread

  for (int k0 = 0; k0 < CIN; k0 += 32) {
    { // stage X[m0+rX][k0+cpX .. +8] -> XA bf16
      const float* src = x + (size_t)(m0 + rX) * CIN + k0 + cpX;
      float4 f0 = *reinterpret_cast<const float4*>(src);
      float4 f1 = *reinterpret_cast<const float4*>(src + 4);
      uint4 pk;
      pk.x = f2bf(f0.x) | ((unsigned)f2bf(f0.y) << 16);
      pk.y = f2bf(f0.z) | ((unsigned)f2bf(f0.w) << 16);
      pk.z = f2bf(f1.x) | ((unsigned)f2bf(f1.y) << 16);
      pk.w = f2bf(f1.z) | ((unsigned)f2bf(f1.w) << 16);
      *reinterpret_cast<uint4*>(&XA[rX][cpX]) = pk;
    }
    { // stage W[k0+kW][n0+npW .. +8] transposed -> WT[n][k] bf16
      const float* src = W + (size_t)(k0 + kW) * CIN + n0 + npW;
      float4 f0 = *reinterpret_cast<const float4*>(src);
      float4 f1 = *reinterpret_cast<const float4*>(src + 4);
      WT[npW + 0][kW] = f2bf(f0.x);
      WT[npW + 1][kW] = f2bf(f0.y);
      WT[npW + 2][kW] = f2bf(f0.z);
      WT[npW + 3][kW] = f2bf(f0.w);
      WT[npW + 4][kW] = f2bf(f1.x);
      WT[npW + 5][kW] = f2bf(f1.y);
      WT[npW + 6][kW] = f2bf(f1.z);
      WT[npW + 7][kW] = f2bf(f1.w);
    }
    __syncthreads();

    bf16x8 a = ld_bf8(&XA[w * 16 + c][g * 8]);
#pragma unroll
    for (int nt = 0; nt < 4; ++nt) {
      bf16x8 b = ld_bf8(&WT[nt * 16 + c][g * 8]);
      acc[nt] = __builtin_amdgcn_mfma_f32_16x16x32_bf16(a, b, acc[nt], 0, 0, 0);
    }
    __syncthreads();
  }

  // Epilogue: D[row=m0+w*16+4g+i][col=n0+nt*16+c]; split col -> (h,d)
#pragma unroll
  for (int nt = 0; nt < 4; ++nt) {
    const int col = n0 + nt * 16 + c;
    const int h = col >> 6, d = col & 63;
#pragma unroll
    for (int i = 0; i < 4; ++i) {
      const int m = m0 + w * 16 + 4 * g + i;
      const int b = m >> 8, t = m & 255;   // T=256
      const unsigned short val = f2bf(acc[nt][i]);
      if (z == 0)
        q_ws[(((size_t)b * NH + h) * T_SEQ + t) * HS + d] = val;
      else if (z == 1)
        k_ws[(((size_t)b * NH + h) * T_SEQ + t) * HS + d] = val;
      else  // V stored transposed: [bh][d][t]
        vT_ws[(((size_t)b * NH + h) * HS + d) * T_SEQ + t] = val;
    }
  }
}

// ---------------------------------------------------------------------------
// Kernel 2: attention. Block = (qb in 0..3, bh in 0..767), 4 waves.
// Wave w handles q rows [qb*64 + w*16, +16). Causal tile-skip via template QB
// (keeps all accumulator indexing compile-time -> no scratch).
// ---------------------------------------------------------------------------
template<int QB>
__device__ __forceinline__ void attn_body(
    const unsigned short* __restrict__ q_ws,
    const unsigned short* __restrict__ k_ws,
    const unsigned short* __restrict__ vT_ws,
    unsigned short* __restrict__ o_ws,
    int bh, unsigned short* Pl)
{
  constexpr int NT = 4 * (QB + 1);   // QK^T col tiles of 16 (covers s < 64*(QB+1))
  constexpr int KS = 2 * (QB + 1);   // PV k-steps of 32
  const int tid = threadIdx.x;
  const int w = tid >> 6, l = tid & 63, g = l >> 4, c = l & 15;
  const int q0 = QB * 64 + w * 16;   // global q-row base for this wave

  // Q A-fragments (hs=64 -> two k-steps), straight from global (bf16)
  const unsigned short* qbase = q_ws + ((size_t)bh * T_SEQ + q0 + c) * HS;
  const bf16x8 qa0 = ld_bf8(qbase + g * 8);
  const bf16x8 qa1 = ld_bf8(qbase + 32 + g * 8);

  // S = Q K^T : B-frag = K[s0+c][k] read directly from global (L2-resident)
  f32x4 s[NT];
#pragma unroll
  for (int tk = 0; tk < NT; ++tk) {
    const unsigned short* kb = k_ws + ((size_t)bh * T_SEQ + tk * 16 + c) * HS;
    bf16x8 b0 = ld_bf8(kb + g * 8);
    bf16x8 b1 = ld_bf8(kb + 32 + g * 8);
    f32x4 t4 = {0.f, 0.f, 0.f, 0.f};
    t4 = __builtin_amdgcn_mfma_f32_16x16x32_bf16(qa0, b0, t4, 0, 0, 0);
    t4 = __builtin_amdgcn_mfma_f32_16x16x32_bf16(qa1, b1, t4, 0, 0, 0);
    s[tk] = t4;
  }

  // scale + causal mask + row-softmax. Lane holds rows q0+4g+i, col tk*16+c.
  // One row lives in the 16 lanes sharing g -> shfl_xor 1,2,4,8 reduces it.
  const float scale = 0.05103103630798288f;  // 384^-0.5 (ref scales by C, not hs)
  float mx[4] = {-1e30f, -1e30f, -1e30f, -1e30f};
#pragma unroll
  for (int tk = 0; tk < NT; ++tk)
#pragma unroll
    for (int i = 0; i < 4; ++i) {
      float v = s[tk][i] * scale;
      const int col = tk * 16 + c;
      const int row = q0 + 4 * g + i;
      v = (col <= row) ? v : -1e30f;
      s[tk][i] = v;
      mx[i] = fmaxf(mx[i], v);
    }
#pragma unroll
  for (int i = 0; i < 4; ++i) {
    float v = mx[i];
    v = fmaxf(v, __shfl_xor(v, 1));
    v = fmaxf(v, __shfl_xor(v, 2));
    v = fmaxf(v, __shfl_xor(v, 4));
    v = fmaxf(v, __shfl_xor(v, 8));
    mx[i] = v;
  }
  float sm[4] = {0.f, 0.f, 0.f, 0.f};
#pragma unroll
  for (int tk = 0; tk < NT; ++tk)
#pragma unroll
    for (int i = 0; i < 4; ++i) {
      float p = __expf(s[tk][i] - mx[i]);  // masked: exp(-1e30 - m) -> 0
      s[tk][i] = p;
      sm[i] += p;
    }
#pragma unroll
  for (int i = 0; i < 4; ++i) {
    float v = sm[i];
    v += __shfl_xor(v, 1);
    v += __shfl_xor(v, 2);
    v += __shfl_xor(v, 4);
    v += __shfl_xor(v, 8);
    sm[i] = 1.0f / v;   // rows always have >=1 valid col (s=0<=t)
  }

  // Normalized P -> LDS bf16, rows are wave-private (no __syncthreads needed)
#pragma unroll
  for (int tk = 0; tk < NT; ++tk)
#pragma unroll
    for (int i = 0; i < 4; ++i)
      Pl[(w * 16 + 4 * g + i) * 264 + tk * 16 + c] = f2bf(s[tk][i] * sm[i]);

  // O = P V : A-frag from Pl (row = w*16 + c), B-frag from vT (contiguous)
  f32x4 o[4];
#pragma unroll
  for (int nt = 0; nt < 4; ++nt) { f32x4 zz = {0.f, 0.f, 0.f, 0.f}; o[nt] = zz; }
#pragma unroll
  for (int ks = 0; ks < KS; ++ks) {
    bf16x8 a = ld_bf8(&Pl[(w * 16 + c) * 264 + ks * 32 + g * 8]);
#pragma unroll
    for (int nt = 0; nt < 4; ++nt) {
      const unsigned short* vb =
          vT_ws + ((size_t)bh * HS + nt * 16 + c) * T_SEQ + ks * 32 + g * 8;
      bf16x8 b = ld_bf8(vb);
      o[nt] = __builtin_amdgcn_mfma_f32_16x16x32_bf16(a, b, o[nt], 0, 0, 0);
    }
  }

  // Write O as [B*T, 384] bf16 (heads interleaved for the final GEMM)
  const int b = bh / NH, h = bh % NH;
#pragma unroll
  for (int nt = 0; nt < 4; ++nt)
#pragma unroll
    for (int i = 0; i < 4; ++i) {
      const int trow = q0 + 4 * g + i;
      o_ws[((size_t)(b * T_SEQ + trow)) * CIN + h * HS + nt * 16 + c] =
          f2bf(o[nt][i]);
    }
}

__global__ __launch_bounds__(256) void attn_kernel(
    const unsigned short* __restrict__ q_ws,
    const unsigned short* __restrict__ k_ws,
    const unsigned short* __restrict__ vT_ws,
    unsigned short* __restrict__ o_ws)
{
  __shared__ __align__(16) unsigned short P[64 * 264];  // 33.8 KB
  const int qb = blockIdx.x, bh = blockIdx.y;
  switch (qb) {
    case 0: attn_body<0>(q_ws, k_ws, vT_ws, o_ws, bh, P); break;
    case 1: attn_body<1>(q_ws, k_ws, vT_ws, o_ws, bh, P); break;
    case 2: attn_body<2>(q_ws, k_ws, vT_ws, o_ws, bh, P); break;
    case 3: attn_body<3>(q_ws, k_ws, vT_ws, o_ws, bh, P); break;
  }
}

// ---------------------------------------------------------------------------
// Kernel 3: output projection. out = O @ Wp + bp, f32 out. Same GEMM shape
// as kernel 1 but A is already bf16 (plain 16B copy into LDS).
// ---------------------------------------------------------------------------
__global__ __launch_bounds__(256) void proj_kernel(
    const unsigned short* __restrict__ o_ws,
    const float* __restrict__ Wp,
    const float* __restrict__ bp,
    float* __restrict__ out)
{
  __shared__ __align__(16) unsigned short XA[64][32];
  __shared__ __align__(16) unsigned short WT[64][32];

  const int tid = threadIdx.x;
  const int w = tid >> 6, l = tid & 63, g = l >> 4, c = l & 15;
  const int m0 = blockIdx.x * 64;
  const int n0 = blockIdx.y * 64;

  f32x4 acc[4];
#pragma unroll
  for (int nt = 0; nt < 4; ++nt) { f32x4 zz = {0.f, 0.f, 0.f, 0.f}; acc[nt] = zz; }

  const int rX = tid >> 2, cpX = (tid & 3) * 8;
  const int kW = tid >> 3, npW = (tid & 7) * 8;

  for (int k0 = 0; k0 < CIN; k0 += 32) {
    *reinterpret_cast<uint4*>(&XA[rX][cpX]) =
        *reinterpret_cast<const uint4*>(o_ws + (size_t)(m0 + rX) * CIN + k0 + cpX);
    {
      const float* src = Wp + (size_t)(k0 + kW) * CIN + n0 + npW;
      float4 f0 = *reinterpret_cast<const float4*>(src);
      float4 f1 = *reinterpret_cast<const float4*>(src + 4);
      WT[npW + 0][kW] = f2bf(f0.x);
      WT[npW + 1][kW] = f2bf(f0.y);
      WT[npW + 2][kW] = f2bf(f0.z);
      WT[npW + 3][kW] = f2bf(f0.w);
      WT[npW + 4][kW] = f2bf(f1.x);
      WT[npW + 5][kW] = f2bf(f1.y);
      WT[npW + 6][kW] = f2bf(f1.z);
      WT[npW + 7][kW] = f2bf(f1.w);
    }
    __syncthreads();

    bf16x8 a = ld_bf8(&XA[w * 16 + c][g * 8]);
#pragma unroll
    for (int nt = 0; nt < 4; ++nt) {
      bf16x8 b = ld_bf8(&WT[nt * 16 + c][g * 8]);
      acc[nt] = __builtin_amdgcn_mfma_f32_16x16x32_bf16(a, b, acc[nt], 0, 0, 0);
    }
    __syncthreads();
  }

#pragma unroll
  for (int nt = 0; nt < 4; ++nt) {
    const int col = n0 + nt * 16 + c;
    const float bias = bp[col];
#pragma unroll
    for (int i = 0; i < 4; ++i) {
      const int m = m0 + w * 16 + 4 * g + i;
      out[(size_t)m * CIN + col] = acc[nt][i] + bias;
    }
  }
}

// ---------------------------------------------------------------------------
extern "C" void kernel_launch(void* const* d_in, const int* in_sizes, int n_in,
                              void* d_out, int out_size, void* d_ws, size_t ws_size,
                              hipStream_t stream)
{
  // setup_inputs order: x, Wk, Wq, Wv, Wp, bp
  const float* x  = (const float*)d_in[0];
  const float* Wk = (const float*)d_in[1];
  const float* Wq = (const float*)d_in[2];
  const float* Wv = (const float*)d_in[3];
  const float* Wp = (const float*)d_in[4];
  const float* bp = (const float*)d_in[5];
  float* out = (float*)d_out;

  unsigned short* ws    = (unsigned short*)d_ws;
  unsigned short* q_ws  = ws;
  unsigned short* k_ws  = ws + ELEMS;
  unsigned short* vT_ws = ws + 2 * ELEMS;
  unsigned short* o_ws  = ws + 3 * ELEMS;
  // requires ws_size >= 4 * ELEMS * 2 = 100,663,296 bytes

  qkv_kernel<<<dim3(BT / 64, CIN / 64, 3), 256, 0, stream>>>(
      x, Wq, Wk, Wv, q_ws, k_ws, vT_ws);
  attn_kernel<<<dim3(4, BATCH * NH), 256, 0, stream>>>(q_ws, k_ws, vT_ws, o_ws);
  proj_kernel<<<dim3(BT / 64, CIN / 64), 256, 0, stream>>>(o_ws, Wp, bp, out);
}

// Round 2
// 193.629 us; speedup vs baseline: 1.5950x; 1.5950x over previous
//
#include <hip/hip_runtime.h>

// MultiHeadAttention forward, MI355X gfx950.  B=128,T=256,C=384,H=6,hs=64.
//
// Pipeline:
//   0) convert_x    : x f32 -> bf16                       (buf0)
//   1) convert_wqkv : Wq|Wk|Wv f32 -> transposed bf16 [1152][384] (d_out scratch)
//   2) gemm_qkv     : fused QKV GEMM 32768x1152, 128x128 tile, global_load_lds,
//                     XCD-chunked swizzle; scatter-epilogue -> q,k,vT (bf16)
//   3) attn_kernel  : causal attention per (qtile, b*h); o -> buf0 (x dead)
//   4) transpose_w  : Wp -> bf16 [384][384] into q region (q dead)
//   5) proj         : out = o @ Wp + bp (f32), same GEMM structure
//
// ws usage: exactly 4 * 32768*384 * 2B = 100,663,296 bytes (proven size).

#define T_SEQ 256
#define NH 6
#define HS 64
#define CIN 384
#define NQKV 1152
#define BATCH 128
#define BT (BATCH * T_SEQ)            // 32768
#define ELEMS ((size_t)BT * CIN)      // 12,582,912 per buffer

using f32x4  = __attribute__((ext_vector_type(4))) float;
using bf16x8 = __attribute__((ext_vector_type(8))) short;  // 8 bf16 in 4 VGPRs

typedef __attribute__((address_space(3))) void       lds_vp;
typedef __attribute__((address_space(1))) const void glob_vp;

// f32 -> bf16 round-to-nearest-even
static __device__ __forceinline__ unsigned short f2bf(float f) {
  union { float f; unsigned u; } v; v.f = f;
  unsigned r = v.u + 0x7FFFu + ((v.u >> 16) & 1u);
  return (unsigned short)(r >> 16);
}

static __device__ __forceinline__ bf16x8 ld_bf8(const unsigned short* p) {
  return *reinterpret_cast<const bf16x8*>(p);
}

static __device__ __forceinline__ void gl_lds16(const void* g, void* l) {
  __builtin_amdgcn_global_load_lds((glob_vp*)g, (lds_vp*)l, 16, 0, 0);
}

// ---------------------------------------------------------------------------
// 0) x f32 -> bf16.  6144 blocks x 256 thr x 8 elems = 12,582,912 exactly.
// ---------------------------------------------------------------------------
__global__ __launch_bounds__(256) void convert_x(
    const float* __restrict__ x, unsigned short* __restrict__ xb)
{
  size_t i = (((size_t)blockIdx.x << 8) + threadIdx.x) << 3;
  float4 f0 = *reinterpret_cast<const float4*>(x + i);
  float4 f1 = *reinterpret_cast<const float4*>(x + i + 4);
  uint4 pk;
  pk.x = f2bf(f0.x) | ((unsigned)f2bf(f0.y) << 16);
  pk.y = f2bf(f0.z) | ((unsigned)f2bf(f0.w) << 16);
  pk.z = f2bf(f1.x) | ((unsigned)f2bf(f1.y) << 16);
  pk.w = f2bf(f1.z) | ((unsigned)f2bf(f1.w) << 16);
  *reinterpret_cast<uint4*>(xb + i) = pk;
}

// ---------------------------------------------------------------------------
// 1) Wq/Wk/Wv f32 [384][384] -> bf16 transposed [z*384 + n][k].  grid(12,12,3).
// ---------------------------------------------------------------------------
__global__ __launch_bounds__(256) void convert_wqkv(
    const float* __restrict__ Wq, const float* __restrict__ Wk,
    const float* __restrict__ Wv, unsigned short* __restrict__ dst)
{
  __shared__ float t[32][33];
  const int z = blockIdx.z;
  const float* __restrict__ W = (z == 0) ? Wq : (z == 1) ? Wk : Wv;
  const int tx = threadIdx.x & 31, ty = threadIdx.x >> 5;  // ty 0..7
  const int k0 = blockIdx.x * 32, n0 = blockIdx.y * 32;
#pragma unroll
  for (int i = 0; i < 4; ++i)
    t[ty + 8 * i][tx] = W[(size_t)(k0 + ty + 8 * i) * CIN + n0 + tx];
  __syncthreads();
#pragma unroll
  for (int i = 0; i < 4; ++i)
    dst[((size_t)z * CIN + n0 + ty + 8 * i) * CIN + k0 + tx] =
        f2bf(t[tx][ty + 8 * i]);
}

// 4) Wp -> bf16 transposed [n][k] into dst.  grid(12,12).
__global__ __launch_bounds__(256) void transpose_w(
    const float* __restrict__ W, unsigned short* __restrict__ dst)
{
  __shared__ float t[32][33];
  const int tx = threadIdx.x & 31, ty = threadIdx.x >> 5;
  const int k0 = blockIdx.x * 32, n0 = blockIdx.y * 32;
#pragma unroll
  for (int i = 0; i < 4; ++i)
    t[ty + 8 * i][tx] = W[(size_t)(k0 + ty + 8 * i) * CIN + n0 + tx];
  __syncthreads();
#pragma unroll
  for (int i = 0; i < 4; ++i)
    dst[((size_t)(n0 + ty + 8 * i)) * CIN + k0 + tx] = f2bf(t[tx][ty + 8 * i]);
}

// ---------------------------------------------------------------------------
// 2) Fused QKV GEMM.  A = xb [32768][384] bf16, Bt = wqkvT [1152][384] bf16.
// 128x128 tile, BK=64, 4 waves (2x2), each wave 64x64 = 4x4 16x16 frags.
// global_load_lds width 16 for all staging.  Chunked XCD swizzle (2304=8*288).
// MFMA layouts (verified m89/m91):
//   A: lane l holds A[l&15][8*(l>>4)+j] ; B: lane l holds B[8*(l>>4)+j][l&15]
//   D: lane l holds D[4*(l>>4)+i][l&15]
// ---------------------------------------------------------------------------
__global__ __launch_bounds__(256) void gemm_qkv(
    const unsigned short* __restrict__ xb,
    const unsigned short* __restrict__ wt,
    unsigned short* __restrict__ q_ws, unsigned short* __restrict__ k_ws,
    unsigned short* __restrict__ vT_ws)
{
  __shared__ __align__(16) unsigned short XA[128][64];  // 16 KB
  __shared__ __align__(16) unsigned short XB[128][64];  // 16 KB

  const int tid = threadIdx.x;
  const int w = tid >> 6, l = tid & 63, g = l >> 4, c = l & 15;
  const int wr = w >> 1, wc = w & 1;

  const int wid = ((int)blockIdx.x & 7) * 288 + ((int)blockIdx.x >> 3);
  const int n_t = wid % 9, m_t = wid / 9;
  const int m0 = m_t * 128, n0 = n_t * 128;

  f32x4 acc[4][4];
#pragma unroll
  for (int mi = 0; mi < 4; ++mi)
#pragma unroll
    for (int nj = 0; nj < 4; ++nj) { f32x4 zz = {0.f,0.f,0.f,0.f}; acc[mi][nj] = zz; }

  // staging: wave w owns rows [w*32, w*32+32) of both tiles; 4 issues each
  const unsigned short* ga = xb + (size_t)(m0 + (w << 5) + (l >> 3)) * CIN + ((l & 7) << 3);
  const unsigned short* gb = wt + (size_t)(n0 + (w << 5) + (l >> 3)) * CIN + ((l & 7) << 3);
  char* lA = (char*)&XA[0][0] + (w << 12);
  char* lB = (char*)&XB[0][0] + (w << 12);

  for (int k0 = 0; k0 < CIN; k0 += 64) {
#pragma unroll
    for (int i = 0; i < 4; ++i) {
      gl_lds16(ga + k0 + i * 8 * CIN, lA + i * 1024);
      gl_lds16(gb + k0 + i * 8 * CIN, lB + i * 1024);
    }
    __syncthreads();
#pragma unroll
    for (int kk = 0; kk < 2; ++kk) {
      bf16x8 a[4], b[4];
#pragma unroll
      for (int mi = 0; mi < 4; ++mi)
        a[mi] = ld_bf8(&XA[wr * 64 + mi * 16 + c][kk * 32 + g * 8]);
#pragma unroll
      for (int nj = 0; nj < 4; ++nj)
        b[nj] = ld_bf8(&XB[wc * 64 + nj * 16 + c][kk * 32 + g * 8]);
#pragma unroll
      for (int mi = 0; mi < 4; ++mi)
#pragma unroll
        for (int nj = 0; nj < 4; ++nj)
          acc[mi][nj] = __builtin_amdgcn_mfma_f32_16x16x32_bf16(
              a[mi], b[nj], acc[mi][nj], 0, 0, 0);
    }
    __syncthreads();
  }

  // scatter epilogue: col -> (z, h, d); z picks q/k/vT
  const int z = n_t / 3;
  const int colw = (n_t % 3) * 128 + wc * 64;  // within [0,384)
#pragma unroll
  for (int nj = 0; nj < 4; ++nj) {
    const int cw = colw + nj * 16 + c;
    const int h = cw >> 6, d = cw & 63;
#pragma unroll
    for (int mi = 0; mi < 4; ++mi) {
      const int mrow = m0 + wr * 64 + mi * 16 + 4 * g;   // +i, i=0..3
      const int b = mrow >> 8, t0 = mrow & 255;
      if (z == 2) {  // vT[(bh*64+d)*256 + t], 4 consecutive t -> 8B store
        ushort4 pk;
        pk.x = f2bf(acc[mi][nj][0]); pk.y = f2bf(acc[mi][nj][1]);
        pk.z = f2bf(acc[mi][nj][2]); pk.w = f2bf(acc[mi][nj][3]);
        *reinterpret_cast<ushort4*>(
            vT_ws + (((size_t)b * NH + h) * HS + d) * T_SEQ + t0) = pk;
      } else {
        unsigned short* dstb = (z == 0) ? q_ws : k_ws;
#pragma unroll
        for (int i = 0; i < 4; ++i)
          dstb[(((size_t)b * NH + h) * T_SEQ + t0 + i) * HS + d] =
              f2bf(acc[mi][nj][i]);
      }
    }
  }
}

// ---------------------------------------------------------------------------
// 3) attention (unchanged from round 1 — passed).  Block=(qb, bh), 4 waves.
// ---------------------------------------------------------------------------
template<int QB>
__device__ __forceinline__ void attn_body(
    const unsigned short* __restrict__ q_ws,
    const unsigned short* __restrict__ k_ws,
    const unsigned short* __restrict__ vT_ws,
    unsigned short* __restrict__ o_ws,
    int bh, unsigned short* Pl)
{
  constexpr int NT = 4 * (QB + 1);
  constexpr int KS = 2 * (QB + 1);
  const int tid = threadIdx.x;
  const int w = tid >> 6, l = tid & 63, g = l >> 4, c = l & 15;
  const int q0 = QB * 64 + w * 16;

  const unsigned short* qbase = q_ws + ((size_t)bh * T_SEQ + q0 + c) * HS;
  const bf16x8 qa0 = ld_bf8(qbase + g * 8);
  const bf16x8 qa1 = ld_bf8(qbase + 32 + g * 8);

  f32x4 s[NT];
#pragma unroll
  for (int tk = 0; tk < NT; ++tk) {
    const unsigned short* kb = k_ws + ((size_t)bh * T_SEQ + tk * 16 + c) * HS;
    bf16x8 b0 = ld_bf8(kb + g * 8);
    bf16x8 b1 = ld_bf8(kb + 32 + g * 8);
    f32x4 t4 = {0.f, 0.f, 0.f, 0.f};
    t4 = __builtin_amdgcn_mfma_f32_16x16x32_bf16(qa0, b0, t4, 0, 0, 0);
    t4 = __builtin_amdgcn_mfma_f32_16x16x32_bf16(qa1, b1, t4, 0, 0, 0);
    s[tk] = t4;
  }

  const float scale = 0.05103103630798288f;  // 384^-0.5
  float mx[4] = {-1e30f, -1e30f, -1e30f, -1e30f};
#pragma unroll
  for (int tk = 0; tk < NT; ++tk)
#pragma unroll
    for (int i = 0; i < 4; ++i) {
      float v = s[tk][i] * scale;
      const int col = tk * 16 + c;
      const int row = q0 + 4 * g + i;
      v = (col <= row) ? v : -1e30f;
      s[tk][i] = v;
      mx[i] = fmaxf(mx[i], v);
    }
#pragma unroll
  for (int i = 0; i < 4; ++i) {
    float v = mx[i];
    v = fmaxf(v, __shfl_xor(v, 1));
    v = fmaxf(v, __shfl_xor(v, 2));
    v = fmaxf(v, __shfl_xor(v, 4));
    v = fmaxf(v, __shfl_xor(v, 8));
    mx[i] = v;
  }
  float sm[4] = {0.f, 0.f, 0.f, 0.f};
#pragma unroll
  for (int tk = 0; tk < NT; ++tk)
#pragma unroll
    for (int i = 0; i < 4; ++i) {
      float p = __expf(s[tk][i] - mx[i]);
      s[tk][i] = p;
      sm[i] += p;
    }
#pragma unroll
  for (int i = 0; i < 4; ++i) {
    float v = sm[i];
    v += __shfl_xor(v, 1);
    v += __shfl_xor(v, 2);
    v += __shfl_xor(v, 4);
    v += __shfl_xor(v, 8);
    sm[i] = 1.0f / v;
  }

#pragma unroll
  for (int tk = 0; tk < NT; ++tk)
#pragma unroll
    for (int i = 0; i < 4; ++i)
      Pl[(w * 16 + 4 * g + i) * 264 + tk * 16 + c] = f2bf(s[tk][i] * sm[i]);

  f32x4 o[4];
#pragma unroll
  for (int nt = 0; nt < 4; ++nt) { f32x4 zz = {0.f, 0.f, 0.f, 0.f}; o[nt] = zz; }
#pragma unroll
  for (int ks = 0; ks < KS; ++ks) {
    bf16x8 a = ld_bf8(&Pl[(w * 16 + c) * 264 + ks * 32 + g * 8]);
#pragma unroll
    for (int nt = 0; nt < 4; ++nt) {
      const unsigned short* vb =
          vT_ws + ((size_t)bh * HS + nt * 16 + c) * T_SEQ + ks * 32 + g * 8;
      bf16x8 b = ld_bf8(vb);
      o[nt] = __builtin_amdgcn_mfma_f32_16x16x32_bf16(a, b, o[nt], 0, 0, 0);
    }
  }

  const int b = bh / NH, h = bh % NH;
#pragma unroll
  for (int nt = 0; nt < 4; ++nt)
#pragma unroll
    for (int i = 0; i < 4; ++i) {
      const int trow = q0 + 4 * g + i;
      o_ws[((size_t)(b * T_SEQ + trow)) * CIN + h * HS + nt * 16 + c] =
          f2bf(o[nt][i]);
    }
}

__global__ __launch_bounds__(256) void attn_kernel(
    const unsigned short* __restrict__ q_ws,
    const unsigned short* __restrict__ k_ws,
    const unsigned short* __restrict__ vT_ws,
    unsigned short* __restrict__ o_ws)
{
  __shared__ __align__(16) unsigned short P[64 * 264];
  const int qb = blockIdx.x, bh = blockIdx.y;
  switch (qb) {
    case 0: attn_body<0>(q_ws, k_ws, vT_ws, o_ws, bh, P); break;
    case 1: attn_body<1>(q_ws, k_ws, vT_ws, o_ws, bh, P); break;
    case 2: attn_body<2>(q_ws, k_ws, vT_ws, o_ws, bh, P); break;
    case 3: attn_body<3>(q_ws, k_ws, vT_ws, o_ws, bh, P); break;
  }
}

// ---------------------------------------------------------------------------
// 5) output projection: out = o @ Wp + bp (f32).  Same GEMM structure; N=384.
// ---------------------------------------------------------------------------
__global__ __launch_bounds__(256) void proj_kernel(
    const unsigned short* __restrict__ ob,
    const unsigned short* __restrict__ wpt,
    const float* __restrict__ bp,
    float* __restrict__ out)
{
  __shared__ __align__(16) unsigned short XA[128][64];
  __shared__ __align__(16) unsigned short XB[128][64];

  const int tid = threadIdx.x;
  const int w = tid >> 6, l = tid & 63, g = l >> 4, c = l & 15;
  const int wr = w >> 1, wc = w & 1;

  const int wid = ((int)blockIdx.x & 7) * 96 + ((int)blockIdx.x >> 3);
  const int n_t = wid % 3, m_t = wid / 3;
  const int m0 = m_t * 128, n0 = n_t * 128;

  f32x4 acc[4][4];
#pragma unroll
  for (int mi = 0; mi < 4; ++mi)
#pragma unroll
    for (int nj = 0; nj < 4; ++nj) { f32x4 zz = {0.f,0.f,0.f,0.f}; acc[mi][nj] = zz; }

  const unsigned short* ga = ob  + (size_t)(m0 + (w << 5) + (l >> 3)) * CIN + ((l & 7) << 3);
  const unsigned short* gb = wpt + (size_t)(n0 + (w << 5) + (l >> 3)) * CIN + ((l & 7) << 3);
  char* lA = (char*)&XA[0][0] + (w << 12);
  char* lB = (char*)&XB[0][0] + (w << 12);

  for (int k0 = 0; k0 < CIN; k0 += 64) {
#pragma unroll
    for (int i = 0; i < 4; ++i) {
      gl_lds16(ga + k0 + i * 8 * CIN, lA + i * 1024);
      gl_lds16(gb + k0 + i * 8 * CIN, lB + i * 1024);
    }
    __syncthreads();
#pragma unroll
    for (int kk = 0; kk < 2; ++kk) {
      bf16x8 a[4], b[4];
#pragma unroll
      for (int mi = 0; mi < 4; ++mi)
        a[mi] = ld_bf8(&XA[wr * 64 + mi * 16 + c][kk * 32 + g * 8]);
#pragma unroll
      for (int nj = 0; nj < 4; ++nj)
        b[nj] = ld_bf8(&XB[wc * 64 + nj * 16 + c][kk * 32 + g * 8]);
#pragma unroll
      for (int mi = 0; mi < 4; ++mi)
#pragma unroll
        for (int nj = 0; nj < 4; ++nj)
          acc[mi][nj] = __builtin_amdgcn_mfma_f32_16x16x32_bf16(
              a[mi], b[nj], acc[mi][nj], 0, 0, 0);
    }
    __syncthreads();
  }

#pragma unroll
  for (int nj = 0; nj < 4; ++nj) {
    const int col = n0 + wc * 64 + nj * 16 + c;
    const float bias = bp[col];
#pragma unroll
    for (int mi = 0; mi < 4; ++mi) {
      const int mrow = m0 + wr * 64 + mi * 16 + 4 * g;
#pragma unroll
      for (int i = 0; i < 4; ++i)
        out[(size_t)(mrow + i) * CIN + col] = acc[mi][nj][i] + bias;
    }
  }
}

// ---------------------------------------------------------------------------
extern "C" void kernel_launch(void* const* d_in, const int* in_sizes, int n_in,
                              void* d_out, int out_size, void* d_ws, size_t ws_size,
                              hipStream_t stream)
{
  // setup_inputs order: x, Wk, Wq, Wv, Wp, bp
  const float* x  = (const float*)d_in[0];
  const float* Wk = (const float*)d_in[1];
  const float* Wq = (const float*)d_in[2];
  const float* Wv = (const float*)d_in[3];
  const float* Wp = (const float*)d_in[4];
  const float* bp = (const float*)d_in[5];
  float* out = (float*)d_out;

  unsigned short* ws    = (unsigned short*)d_ws;
  unsigned short* xb_o  = ws;              // x_bf16; aliased as o after qkv
  unsigned short* q_ws  = ws + ELEMS;      // q; aliased as WpT after attn
  unsigned short* k_ws  = ws + 2 * ELEMS;
  unsigned short* vT_ws = ws + 3 * ELEMS;
  unsigned short* wqkvT = (unsigned short*)d_out;  // 884,736 B scratch (pre-proj)

  convert_x   <<<6144, 256, 0, stream>>>(x, xb_o);
  convert_wqkv<<<dim3(12, 12, 3), 256, 0, stream>>>(Wq, Wk, Wv, wqkvT);
  gemm_qkv    <<<2304, 256, 0, stream>>>(xb_o, wqkvT, q_ws, k_ws, vT_ws);
  attn_kernel <<<dim3(4, BATCH * NH), 256, 0, stream>>>(q_ws, k_ws, vT_ws, xb_o);
  transpose_w <<<dim3(12, 12), 256, 0, stream>>>(Wp, q_ws);
  proj_kernel <<<768, 256, 0, stream>>>(xb_o, q_ws, bp, out);
}

// Round 3
// 130.054 us; speedup vs baseline: 2.3747x; 1.4888x over previous
//
#include <hip/hip_runtime.h>
#include <hip/hip_bf16.h>

// MultiHeadAttention forward, MI355X gfx950.  B=128,T=256,C=384,H=6,hs=64.
//
// Pipeline:
//   0) convert_x    : x f32 -> bf16                       (buf0)
//   1) convert_wqkv : Wq|Wk|Wv f32 -> transposed bf16 [1152][384] (d_out scratch)
//   2) gemm_qkv     : fused QKV GEMM 32768x1152, 128x128 tile, global_load_lds
//   3) attn_kernel  : 1 block/bh, 8 waves; K+Vt in swizzled LDS; swapped QK^T;
//                     in-register softmax + shfl-based P->A-frag; o -> buf0
//   4) transpose_w  : Wp -> bf16 [384][384] into q region (q dead)
//   5) proj         : out = o @ Wp + bp (f32)
//
// ws usage: exactly 4 * 32768*384 * 2B = 100,663,296 bytes.

#define T_SEQ 256
#define NH 6
#define HS 64
#define CIN 384
#define BATCH 128
#define BT (BATCH * T_SEQ)            // 32768
#define ELEMS ((size_t)BT * CIN)      // 12,582,912 per buffer

using f32x4  = __attribute__((ext_vector_type(4))) float;
using bf16x8 = __attribute__((ext_vector_type(8))) short;  // 8 bf16 in 4 VGPRs

typedef __attribute__((address_space(3))) void       lds_vp;
typedef __attribute__((address_space(1))) const void glob_vp;

// f32 -> bf16 round-to-nearest-even
static __device__ __forceinline__ unsigned short f2bf(float f) {
  union { float f; unsigned u; } v; v.f = f;
  unsigned r = v.u + 0x7FFFu + ((v.u >> 16) & 1u);
  return (unsigned short)(r >> 16);
}

static __device__ __forceinline__ bf16x8 ld_bf8(const unsigned short* p) {
  return *reinterpret_cast<const bf16x8*>(p);
}

static __device__ __forceinline__ void gl_lds16(const void* g, void* l) {
  __builtin_amdgcn_global_load_lds((glob_vp*)g, (lds_vp*)l, 16, 0, 0);
}

// ---------------------------------------------------------------------------
// 0) x f32 -> bf16.
// ---------------------------------------------------------------------------
__global__ __launch_bounds__(256) void convert_x(
    const float* __restrict__ x, unsigned short* __restrict__ xb)
{
  size_t i = (((size_t)blockIdx.x << 8) + threadIdx.x) << 3;
  float4 f0 = *reinterpret_cast<const float4*>(x + i);
  float4 f1 = *reinterpret_cast<const float4*>(x + i + 4);
  uint4 pk;
  pk.x = f2bf(f0.x) | ((unsigned)f2bf(f0.y) << 16);
  pk.y = f2bf(f0.z) | ((unsigned)f2bf(f0.w) << 16);
  pk.z = f2bf(f1.x) | ((unsigned)f2bf(f1.y) << 16);
  pk.w = f2bf(f1.z) | ((unsigned)f2bf(f1.w) << 16);
  *reinterpret_cast<uint4*>(xb + i) = pk;
}

// ---------------------------------------------------------------------------
// 1) Wq/Wk/Wv f32 [384][384] -> bf16 transposed [z*384 + n][k].  grid(12,12,3).
// ---------------------------------------------------------------------------
__global__ __launch_bounds__(256) void convert_wqkv(
    const float* __restrict__ Wq, const float* __restrict__ Wk,
    const float* __restrict__ Wv, unsigned short* __restrict__ dst)
{
  __shared__ float t[32][33];
  const int z = blockIdx.z;
  const float* __restrict__ W = (z == 0) ? Wq : (z == 1) ? Wk : Wv;
  const int tx = threadIdx.x & 31, ty = threadIdx.x >> 5;
  const int k0 = blockIdx.x * 32, n0 = blockIdx.y * 32;
#pragma unroll
  for (int i = 0; i < 4; ++i)
    t[ty + 8 * i][tx] = W[(size_t)(k0 + ty + 8 * i) * CIN + n0 + tx];
  __syncthreads();
#pragma unroll
  for (int i = 0; i < 4; ++i)
    dst[((size_t)z * CIN + n0 + ty + 8 * i) * CIN + k0 + tx] =
        f2bf(t[tx][ty + 8 * i]);
}

// 4) Wp -> bf16 transposed [n][k].  grid(12,12).
__global__ __launch_bounds__(256) void transpose_w(
    const float* __restrict__ W, unsigned short* __restrict__ dst)
{
  __shared__ float t[32][33];
  const int tx = threadIdx.x & 31, ty = threadIdx.x >> 5;
  const int k0 = blockIdx.x * 32, n0 = blockIdx.y * 32;
#pragma unroll
  for (int i = 0; i < 4; ++i)
    t[ty + 8 * i][tx] = W[(size_t)(k0 + ty + 8 * i) * CIN + n0 + tx];
  __syncthreads();
#pragma unroll
  for (int i = 0; i < 4; ++i)
    dst[((size_t)(n0 + ty + 8 * i)) * CIN + k0 + tx] = f2bf(t[tx][ty + 8 * i]);
}

// ---------------------------------------------------------------------------
// 2) Fused QKV GEMM (unchanged from round 2).
// ---------------------------------------------------------------------------
__global__ __launch_bounds__(256) void gemm_qkv(
    const unsigned short* __restrict__ xb,
    const unsigned short* __restrict__ wt,
    unsigned short* __restrict__ q_ws, unsigned short* __restrict__ k_ws,
    unsigned short* __restrict__ vT_ws)
{
  __shared__ __align__(16) unsigned short XA[128][64];
  __shared__ __align__(16) unsigned short XB[128][64];

  const int tid = threadIdx.x;
  const int w = tid >> 6, l = tid & 63, g = l >> 4, c = l & 15;
  const int wr = w >> 1, wc = w & 1;

  const int wid = ((int)blockIdx.x & 7) * 288 + ((int)blockIdx.x >> 3);
  const int n_t = wid % 9, m_t = wid / 9;
  const int m0 = m_t * 128, n0 = n_t * 128;

  f32x4 acc[4][4];
#pragma unroll
  for (int mi = 0; mi < 4; ++mi)
#pragma unroll
    for (int nj = 0; nj < 4; ++nj) { f32x4 zz = {0.f,0.f,0.f,0.f}; acc[mi][nj] = zz; }

  const unsigned short* ga = xb + (size_t)(m0 + (w << 5) + (l >> 3)) * CIN + ((l & 7) << 3);
  const unsigned short* gb = wt + (size_t)(n0 + (w << 5) + (l >> 3)) * CIN + ((l & 7) << 3);
  char* lA = (char*)&XA[0][0] + (w << 12);
  char* lB = (char*)&XB[0][0] + (w << 12);

  for (int k0 = 0; k0 < CIN; k0 += 64) {
#pragma unroll
    for (int i = 0; i < 4; ++i) {
      gl_lds16(ga + k0 + i * 8 * CIN, lA + i * 1024);
      gl_lds16(gb + k0 + i * 8 * CIN, lB + i * 1024);
    }
    __syncthreads();
#pragma unroll
    for (int kk = 0; kk < 2; ++kk) {
      bf16x8 a[4], b[4];
#pragma unroll
      for (int mi = 0; mi < 4; ++mi)
        a[mi] = ld_bf8(&XA[wr * 64 + mi * 16 + c][kk * 32 + g * 8]);
#pragma unroll
      for (int nj = 0; nj < 4; ++nj)
        b[nj] = ld_bf8(&XB[wc * 64 + nj * 16 + c][kk * 32 + g * 8]);
#pragma unroll
      for (int mi = 0; mi < 4; ++mi)
#pragma unroll
        for (int nj = 0; nj < 4; ++nj)
          acc[mi][nj] = __builtin_amdgcn_mfma_f32_16x16x32_bf16(
              a[mi], b[nj], acc[mi][nj], 0, 0, 0);
    }
    __syncthreads();
  }

  const int z = n_t / 3;
  const int colw = (n_t % 3) * 128 + wc * 64;
#pragma unroll
  for (int nj = 0; nj < 4; ++nj) {
    const int cw = colw + nj * 16 + c;
    const int h = cw >> 6, d = cw & 63;
#pragma unroll
    for (int mi = 0; mi < 4; ++mi) {
      const int mrow = m0 + wr * 64 + mi * 16 + 4 * g;
      const int b = mrow >> 8, t0 = mrow & 255;
      if (z == 2) {
        ushort4 pk;
        pk.x = f2bf(acc[mi][nj][0]); pk.y = f2bf(acc[mi][nj][1]);
        pk.z = f2bf(acc[mi][nj][2]); pk.w = f2bf(acc[mi][nj][3]);
        *reinterpret_cast<ushort4*>(
            vT_ws + (((size_t)b * NH + h) * HS + d) * T_SEQ + t0) = pk;
      } else {
        unsigned short* dstb = (z == 0) ? q_ws : k_ws;
#pragma unroll
        for (int i = 0; i < 4; ++i)
          dstb[(((size_t)b * NH + h) * T_SEQ + t0 + i) * HS + d] =
              f2bf(acc[mi][nj][i]);
      }
    }
  }
}

// ---------------------------------------------------------------------------
// 3) attention: 1 block/bh, 8 waves.  K, Vt staged in XOR-swizzled LDS.
// Swapped QK^T (S^T = mfma(K,Q)) -> softmax lane-local along regs + 2 shfl.
// P (D-layout) -> PV A-frag via 8 shfl + 4 cndmask per 32-k step.
// Wave w handles q-tiles {w, 15-w} (balanced: 18 k-tiles each).
// Template NT = even # of 16-col k-tiles (padded tiles fully masked).
// ---------------------------------------------------------------------------
template<int NT>
__device__ __forceinline__ void attn_tile(
    const unsigned short* __restrict__ qg,
    const unsigned short* KL, const unsigned short* VL,
    unsigned short* __restrict__ o_ws, int bh, int qt, int g, int c)
{
  const int q0 = qt * 16;
  const int kxor = (c & 7) << 4;

  // Q B-fragments: B[d][q] = Q[q0+c][d], contiguous 16B
  const char* qrow = (const char*)qg + (size_t)(q0 + c) * 128;
  const bf16x8 qb0 = *reinterpret_cast<const bf16x8*>(qrow + g * 16);
  const bf16x8 qb1 = *reinterpret_cast<const bf16x8*>(qrow + 64 + g * 16);

  // S^T tiles: lane (g,c) holds S^T[kt*16+4g+i][q0+c]
  f32x4 s[NT];
#pragma unroll
  for (int kt = 0; kt < NT; ++kt) {
    const char* krow = (const char*)KL + (kt * 16 + c) * 128;
    bf16x8 ka0 = *reinterpret_cast<const bf16x8*>(krow + ((g * 16) ^ kxor));
    bf16x8 ka1 = *reinterpret_cast<const bf16x8*>(krow + ((64 + g * 16) ^ kxor));
    f32x4 z = {0.f, 0.f, 0.f, 0.f};
    z = __builtin_amdgcn_mfma_f32_16x16x32_bf16(ka0, qb0, z, 0, 0, 0);
    z = __builtin_amdgcn_mfma_f32_16x16x32_bf16(ka1, qb1, z, 0, 0, 0);
    s[kt] = z;
  }

  // scale(*log2e) + causal mask + max over k (regs + lanes c, c+16, c+32, c+48)
  const float sc = 0.07362372251839260f;  // 384^-0.5 * log2(e)
  float mx = -1e30f;
#pragma unroll
  for (int kt = 0; kt < NT; ++kt)
#pragma unroll
    for (int i = 0; i < 4; ++i) {
      const int k = kt * 16 + 4 * g + i;
      float v = (k <= q0 + c) ? s[kt][i] * sc : -1e30f;
      s[kt][i] = v;
      mx = fmaxf(mx, v);
    }
  mx = fmaxf(mx, __shfl_xor(mx, 16));
  mx = fmaxf(mx, __shfl_xor(mx, 32));

  float sum = 0.f;
#pragma unroll
  for (int kt = 0; kt < NT; ++kt)
#pragma unroll
    for (int i = 0; i < 4; ++i) {
      float p = __builtin_exp2f(s[kt][i] - mx);
      s[kt][i] = p;
      sum += p;
    }
  sum += __shfl_xor(sum, 16);
  sum += __shfl_xor(sum, 32);
  const float inv = 1.0f / sum;

  // normalize + pack to bf16 pairs (cvt_pk via __float22bfloat162_rn)
  unsigned pk0[NT], pk1[NT];
#pragma unroll
  for (int kt = 0; kt < NT; ++kt) {
    float2 p01 = {s[kt][0] * inv, s[kt][1] * inv};
    float2 p23 = {s[kt][2] * inv, s[kt][3] * inv};
    __hip_bfloat162 b01 = __float22bfloat162_rn(p01);
    __hip_bfloat162 b23 = __float22bfloat162_rn(p23);
    pk0[kt] = *reinterpret_cast<unsigned*>(&b01);
    pk1[kt] = *reinterpret_cast<unsigned*>(&b23);
  }

  // PV: A-frag built by shfl from D-layout P; B-frag = Vt rows from LDS
  f32x4 acc[4];
#pragma unroll
  for (int nt = 0; nt < 4; ++nt) { f32x4 zz = {0.f,0.f,0.f,0.f}; acc[nt] = zz; }

  const int srcA = ((g & 1) << 5) + c;
  const int srcB = srcA + 16;
  const bool hi = (g >= 2);
#pragma unroll
  for (int ks = 0; ks < NT / 2; ++ks) {
    unsigned a0A = __shfl(pk0[2 * ks],     srcA);
    unsigned a1A = __shfl(pk1[2 * ks],     srcA);
    unsigned a0B = __shfl(pk0[2 * ks],     srcB);
    unsigned a1B = __shfl(pk1[2 * ks],     srcB);
    unsigned b0A = __shfl(pk0[2 * ks + 1], srcA);
    unsigned b1A = __shfl(pk1[2 * ks + 1], srcA);
    unsigned b0B = __shfl(pk0[2 * ks + 1], srcB);
    unsigned b1B = __shfl(pk1[2 * ks + 1], srcB);
    union { unsigned u[4]; bf16x8 v; } pa;
    pa.u[0] = hi ? b0A : a0A;
    pa.u[1] = hi ? b1A : a1A;
    pa.u[2] = hi ? b0B : a0B;
    pa.u[3] = hi ? b1B : a1B;
#pragma unroll
    for (int nt = 0; nt < 4; ++nt) {
      const char* vrow = (const char*)VL + (nt * 16 + c) * 512;
      bf16x8 vb = *reinterpret_cast<const bf16x8*>(
          vrow + ((ks * 64 + g * 16) ^ kxor));
      acc[nt] = __builtin_amdgcn_mfma_f32_16x16x32_bf16(pa.v, vb, acc[nt], 0, 0, 0);
    }
  }

  // O write: D[q=4g+i][d=nt*16+c] -> o[b*T + q0+4g+i][h*64 + d]
  const int b = bh / NH, h = bh % NH;
  unsigned short* ob = o_ws + ((size_t)(b * T_SEQ + q0)) * CIN + h * HS;
#pragma unroll
  for (int nt = 0; nt < 4; ++nt)
#pragma unroll
    for (int i = 0; i < 4; ++i)
      ob[(size_t)(4 * g + i) * CIN + nt * 16 + c] = f2bf(acc[nt][i]);
}

__global__ __launch_bounds__(512, 4) void attn_kernel(
    const unsigned short* __restrict__ q_ws,
    const unsigned short* __restrict__ k_ws,
    const unsigned short* __restrict__ vT_ws,
    unsigned short* __restrict__ o_ws)
{
  __shared__ __align__(16) unsigned short KL[256 * 64];  // 32 KB, swizzled
  __shared__ __align__(16) unsigned short VL[64 * 256];  // 32 KB, swizzled

  const int tid = threadIdx.x;
  const int w = tid >> 6, l = tid & 63, g = l >> 4, c = l & 15;
  const int bh = blockIdx.x;

  // stage K and Vt with pre-swizzled global source (linear LDS dest):
  // LDS chunk (row, p) <- global chunk (row, p ^ (row&7))  [low 3 bits only]
  const char* kg = (const char*)(k_ws + (size_t)bh * T_SEQ * HS);
  const char* vg = (const char*)(vT_ws + (size_t)bh * HS * T_SEQ);
#pragma unroll
  for (int i = 0; i < 4; ++i) {
    const int cid = i * 512 + w * 64 + l;
    const int rk = cid >> 3, pk_ = cid & 7;
    gl_lds16(kg + rk * 128 + ((pk_ ^ (rk & 7)) << 4),
             (char*)KL + (size_t)(i * 512 + w * 64) * 16);
    const int rv = cid >> 5, pv = cid & 31;
    const int sv = (pv & ~7) | ((pv & 7) ^ (rv & 7));
    gl_lds16(vg + rv * 512 + (sv << 4),
             (char*)VL + (size_t)(i * 512 + w * 64) * 16);
  }
  __syncthreads();

  const unsigned short* qg = q_ws + (size_t)bh * T_SEQ * HS;
  switch (w) {
    case 0: attn_tile<2>(qg, KL, VL, o_ws, bh, 0, g, c);
            attn_tile<16>(qg, KL, VL, o_ws, bh, 15, g, c); break;
    case 1: attn_tile<2>(qg, KL, VL, o_ws, bh, 1, g, c);
            attn_tile<16>(qg, KL, VL, o_ws, bh, 14, g, c); break;
    case 2: attn_tile<4>(qg, KL, VL, o_ws, bh, 2, g, c);
            attn_tile<14>(qg, KL, VL, o_ws, bh, 13, g, c); break;
    case 3: attn_tile<4>(qg, KL, VL, o_ws, bh, 3, g, c);
            attn_tile<14>(qg, KL, VL, o_ws, bh, 12, g, c); break;
    case 4: attn_tile<6>(qg, KL, VL, o_ws, bh, 4, g, c);
            attn_tile<12>(qg, KL, VL, o_ws, bh, 11, g, c); break;
    case 5: attn_tile<6>(qg, KL, VL, o_ws, bh, 5, g, c);
            attn_tile<12>(qg, KL, VL, o_ws, bh, 10, g, c); break;
    case 6: attn_tile<8>(qg, KL, VL, o_ws, bh, 6, g, c);
            attn_tile<10>(qg, KL, VL, o_ws, bh, 9, g, c); break;
    case 7: attn_tile<8>(qg, KL, VL, o_ws, bh, 7, g, c);
            attn_tile<10>(qg, KL, VL, o_ws, bh, 8, g, c); break;
  }
}

// ---------------------------------------------------------------------------
// 5) output projection (unchanged from round 2).
// ---------------------------------------------------------------------------
__global__ __launch_bounds__(256) void proj_kernel(
    const unsigned short* __restrict__ ob,
    const unsigned short* __restrict__ wpt,
    const float* __restrict__ bp,
    float* __restrict__ out)
{
  __shared__ __align__(16) unsigned short XA[128][64];
  __shared__ __align__(16) unsigned short XB[128][64];

  const int tid = threadIdx.x;
  const int w = tid >> 6, l = tid & 63, g = l >> 4, c = l & 15;
  const int wr = w >> 1, wc = w & 1;

  const int wid = ((int)blockIdx.x & 7) * 96 + ((int)blockIdx.x >> 3);
  const int n_t = wid % 3, m_t = wid / 3;
  const int m0 = m_t * 128, n0 = n_t * 128;

  f32x4 acc[4][4];
#pragma unroll
  for (int mi = 0; mi < 4; ++mi)
#pragma unroll
    for (int nj = 0; nj < 4; ++nj) { f32x4 zz = {0.f,0.f,0.f,0.f}; acc[mi][nj] = zz; }

  const unsigned short* ga = ob  + (size_t)(m0 + (w << 5) + (l >> 3)) * CIN + ((l & 7) << 3);
  const unsigned short* gb = wpt + (size_t)(n0 + (w << 5) + (l >> 3)) * CIN + ((l & 7) << 3);
  char* lA = (char*)&XA[0][0] + (w << 12);
  char* lB = (char*)&XB[0][0] + (w << 12);

  for (int k0 = 0; k0 < CIN; k0 += 64) {
#pragma unroll
    for (int i = 0; i < 4; ++i) {
      gl_lds16(ga + k0 + i * 8 * CIN, lA + i * 1024);
      gl_lds16(gb + k0 + i * 8 * CIN, lB + i * 1024);
    }
    __syncthreads();
#pragma unroll
    for (int kk = 0; kk < 2; ++kk) {
      bf16x8 a[4], b[4];
#pragma unroll
      for (int mi = 0; mi < 4; ++mi)
        a[mi] = ld_bf8(&XA[wr * 64 + mi * 16 + c][kk * 32 + g * 8]);
#pragma unroll
      for (int nj = 0; nj < 4; ++nj)
        b[nj] = ld_bf8(&XB[wc * 64 + nj * 16 + c][kk * 32 + g * 8]);
#pragma unroll
      for (int mi = 0; mi < 4; ++mi)
#pragma unroll
        for (int nj = 0; nj < 4; ++nj)
          acc[mi][nj] = __builtin_amdgcn_mfma_f32_16x16x32_bf16(
              a[mi], b[nj], acc[mi][nj], 0, 0, 0);
    }
    __syncthreads();
  }

#pragma unroll
  for (int nj = 0; nj < 4; ++nj) {
    const int col = n0 + wc * 64 + nj * 16 + c;
    const float bias = bp[col];
#pragma unroll
    for (int mi = 0; mi < 4; ++mi) {
      const int mrow = m0 + wr * 64 + mi * 16 + 4 * g;
#pragma unroll
      for (int i = 0; i < 4; ++i)
        out[(size_t)(mrow + i) * CIN + col] = acc[mi][nj][i] + bias;
    }
  }
}

// ---------------------------------------------------------------------------
extern "C" void kernel_launch(void* const* d_in, const int* in_sizes, int n_in,
                              void* d_out, int out_size, void* d_ws, size_t ws_size,
                              hipStream_t stream)
{
  // setup_inputs order: x, Wk, Wq, Wv, Wp, bp
  const float* x  = (const float*)d_in[0];
  const float* Wk = (const float*)d_in[1];
  const float* Wq = (const float*)d_in[2];
  const float* Wv = (const float*)d_in[3];
  const float* Wp = (const float*)d_in[4];
  const float* bp = (const float*)d_in[5];
  float* out = (float*)d_out;

  unsigned short* ws    = (unsigned short*)d_ws;
  unsigned short* xb_o  = ws;              // x_bf16; aliased as o after qkv
  unsigned short* q_ws  = ws + ELEMS;      // q; aliased as WpT after attn
  unsigned short* k_ws  = ws + 2 * ELEMS;
  unsigned short* vT_ws = ws + 3 * ELEMS;
  unsigned short* wqkvT = (unsigned short*)d_out;  // pre-proj scratch

  convert_x   <<<6144, 256, 0, stream>>>(x, xb_o);
  convert_wqkv<<<dim3(12, 12, 3), 256, 0, stream>>>(Wq, Wk, Wv, wqkvT);
  gemm_qkv    <<<2304, 256, 0, stream>>>(xb_o, wqkvT, q_ws, k_ws, vT_ws);
  attn_kernel <<<BATCH * NH, 512, 0, stream>>>(q_ws, k_ws, vT_ws, xb_o);
  transpose_w <<<dim3(12, 12), 256, 0, stream>>>(Wp, q_ws);
  proj_kernel <<<768, 256, 0, stream>>>(xb_o, q_ws, bp, out);
}

// Round 4
// 119.889 us; speedup vs baseline: 2.5761x; 1.0848x over previous
//
#include <hip/hip_runtime.h>
#include <hip/hip_bf16.h>

// MultiHeadAttention forward, MI355X gfx950.  B=128,T=256,C=384,H=6,hs=64.
//
// Pipeline:
//   0) convert_x    : x f32 -> bf16                       (buf0)
//   1) convert_wqkv : Wq|Wk|Wv f32 -> transposed bf16 [1152][384] (d_out scratch)
//   2) gemm_qkv     : fused QKV GEMM 32768x1152, 128x128 tile, double-buffered
//                     LDS + XOR-swizzle, LDS-coalesced epilogue -> q,k,vT
//   3) attn_kernel  : 1 block/bh, 8 waves; K+Vt in swizzled LDS; swapped QK^T
//   4) transpose_w  : Wp -> bf16 [384][384] into q region (q dead)
//   5) proj         : out = o @ Wp + bp (f32), dbuf+swizzle GEMM
//
// ws usage: exactly 4 * 32768*384 * 2B = 100,663,296 bytes.

#define T_SEQ 256
#define NH 6
#define HS 64
#define CIN 384
#define BATCH 128
#define BT (BATCH * T_SEQ)            // 32768
#define ELEMS ((size_t)BT * CIN)      // 12,582,912 per buffer

using f32x4  = __attribute__((ext_vector_type(4))) float;
using bf16x8 = __attribute__((ext_vector_type(8))) short;  // 8 bf16 in 4 VGPRs

typedef __attribute__((address_space(3))) void       lds_vp;
typedef __attribute__((address_space(1))) const void glob_vp;

// f32 -> bf16 round-to-nearest-even
static __device__ __forceinline__ unsigned short f2bf(float f) {
  union { float f; unsigned u; } v; v.f = f;
  unsigned r = v.u + 0x7FFFu + ((v.u >> 16) & 1u);
  return (unsigned short)(r >> 16);
}

static __device__ __forceinline__ bf16x8 ld_bf8(const unsigned short* p) {
  return *reinterpret_cast<const bf16x8*>(p);
}

static __device__ __forceinline__ void gl_lds16(const void* g, void* l) {
  __builtin_amdgcn_global_load_lds((glob_vp*)g, (lds_vp*)l, 16, 0, 0);
}

// ---------------------------------------------------------------------------
// 0) x f32 -> bf16.
// ---------------------------------------------------------------------------
__global__ __launch_bounds__(256) void convert_x(
    const float* __restrict__ x, unsigned short* __restrict__ xb)
{
  size_t i = (((size_t)blockIdx.x << 8) + threadIdx.x) << 3;
  float4 f0 = *reinterpret_cast<const float4*>(x + i);
  float4 f1 = *reinterpret_cast<const float4*>(x + i + 4);
  uint4 pk;
  pk.x = f2bf(f0.x) | ((unsigned)f2bf(f0.y) << 16);
  pk.y = f2bf(f0.z) | ((unsigned)f2bf(f0.w) << 16);
  pk.z = f2bf(f1.x) | ((unsigned)f2bf(f1.y) << 16);
  pk.w = f2bf(f1.z) | ((unsigned)f2bf(f1.w) << 16);
  *reinterpret_cast<uint4*>(xb + i) = pk;
}

// ---------------------------------------------------------------------------
// 1) Wq/Wk/Wv f32 [384][384] -> bf16 transposed [z*384 + n][k].  grid(12,12,3).
// ---------------------------------------------------------------------------
__global__ __launch_bounds__(256) void convert_wqkv(
    const float* __restrict__ Wq, const float* __restrict__ Wk,
    const float* __restrict__ Wv, unsigned short* __restrict__ dst)
{
  __shared__ float t[32][33];
  const int z = blockIdx.z;
  const float* __restrict__ W = (z == 0) ? Wq : (z == 1) ? Wk : Wv;
  const int tx = threadIdx.x & 31, ty = threadIdx.x >> 5;
  const int k0 = blockIdx.x * 32, n0 = blockIdx.y * 32;
#pragma unroll
  for (int i = 0; i < 4; ++i)
    t[ty + 8 * i][tx] = W[(size_t)(k0 + ty + 8 * i) * CIN + n0 + tx];
  __syncthreads();
#pragma unroll
  for (int i = 0; i < 4; ++i)
    dst[((size_t)z * CIN + n0 + ty + 8 * i) * CIN + k0 + tx] =
        f2bf(t[tx][ty + 8 * i]);
}

// 4) Wp -> bf16 transposed [n][k].  grid(12,12).
__global__ __launch_bounds__(256) void transpose_w(
    const float* __restrict__ W, unsigned short* __restrict__ dst)
{
  __shared__ float t[32][33];
  const int tx = threadIdx.x & 31, ty = threadIdx.x >> 5;
  const int k0 = blockIdx.x * 32, n0 = blockIdx.y * 32;
#pragma unroll
  for (int i = 0; i < 4; ++i)
    t[ty + 8 * i][tx] = W[(size_t)(k0 + ty + 8 * i) * CIN + n0 + tx];
  __syncthreads();
#pragma unroll
  for (int i = 0; i < 4; ++i)
    dst[((size_t)(n0 + ty + 8 * i)) * CIN + k0 + tx] = f2bf(t[tx][ty + 8 * i]);
}

// ---------------------------------------------------------------------------
// 2) Fused QKV GEMM, double-buffered + swizzled.
// LDS layout: XA/XB [buf][128 rows][64 k], row = 128 B = 8 chunks of 16 B.
// Swizzle (involution): LDS[r][chunk p] holds global chunk p ^ (r&7); staging
// pre-swizzles the GLOBAL source address (linear LDS dest, m173 pattern);
// fragment reads XOR the chunk index with (row&7).
// 2-phase loop: STAGE(next) -> compute(cur) -> barrier (drains vmcnt).
// ---------------------------------------------------------------------------
__global__ __launch_bounds__(256) void gemm_qkv(
    const unsigned short* __restrict__ xb,
    const unsigned short* __restrict__ wt,
    unsigned short* __restrict__ q_ws, unsigned short* __restrict__ k_ws,
    unsigned short* __restrict__ vT_ws)
{
  __shared__ __align__(16) unsigned short XA[2][128][64];  // 32 KB
  __shared__ __align__(16) unsigned short XB[2][128][64];  // 32 KB

  const int tid = threadIdx.x;
  const int w = tid >> 6, l = tid & 63, g = l >> 4, c = l & 15;
  const int wr = w >> 1, wc = w & 1;

  const int wid = ((int)blockIdx.x & 7) * 288 + ((int)blockIdx.x >> 3);
  const int n_t = wid % 9, m_t = wid / 9;
  const int m0 = m_t * 128, n0 = n_t * 128;

  f32x4 acc[4][4];
#pragma unroll
  for (int mi = 0; mi < 4; ++mi)
#pragma unroll
    for (int nj = 0; nj < 4; ++nj) { f32x4 zz = {0.f,0.f,0.f,0.f}; acc[mi][nj] = zz; }

  const int lrow = l >> 3;               // 0..7 (row within 8-row group)
  const int lchk = (l & 7) ^ lrow;       // pre-swizzled source chunk
  const char* ga = (const char*)xb +
      ((size_t)(m0 + w * 32 + lrow) * CIN + lchk * 8) * 2;
  const char* gb = (const char*)wt +
      ((size_t)(n0 + w * 32 + lrow) * CIN + lchk * 8) * 2;

#define STAGE_QKV(buf, k0)                                              \
  {                                                                     \
    _Pragma("unroll")                                                   \
    for (int i_ = 0; i_ < 4; ++i_) {                                    \
      gl_lds16(ga + ((k0) + i_ * 8 * CIN) * 2, &XA[buf][w * 32 + i_ * 8][0]); \
      gl_lds16(gb + ((k0) + i_ * 8 * CIN) * 2, &XB[buf][w * 32 + i_ * 8][0]); \
    }                                                                   \
  }

  STAGE_QKV(0, 0);
  __syncthreads();

  int cur = 0;
  for (int t = 0; t < 6; ++t) {
    if (t < 5) STAGE_QKV(cur ^ 1, (t + 1) * 64);
#pragma unroll
    for (int kk = 0; kk < 2; ++kk) {
      bf16x8 a[4], b[4];
#pragma unroll
      for (int mi = 0; mi < 4; ++mi) {
        const int row = wr * 64 + mi * 16 + c;
        a[mi] = *reinterpret_cast<const bf16x8*>(
            (const char*)&XA[cur][row][0] + (((kk * 4 + g) ^ (c & 7)) << 4));
      }
#pragma unroll
      for (int nj = 0; nj < 4; ++nj) {
        const int row = wc * 64 + nj * 16 + c;
        b[nj] = *reinterpret_cast<const bf16x8*>(
            (const char*)&XB[cur][row][0] + (((kk * 4 + g) ^ (c & 7)) << 4));
      }
#pragma unroll
      for (int mi = 0; mi < 4; ++mi)
#pragma unroll
        for (int nj = 0; nj < 4; ++nj)
          acc[mi][nj] = __builtin_amdgcn_mfma_f32_16x16x32_bf16(
              a[mi], b[nj], acc[mi][nj], 0, 0, 0);
    }
    __syncthreads();
    cur ^= 1;
  }

  // Epilogue. Wave's 64 cols = exactly one head (colw 64-aligned).
  const int z = n_t / 3;
  const int colw = (n_t % 3) * 128 + wc * 64;
  const int h = colw >> 6;
  const int b = m0 >> 8;
  const int trow0 = (m0 & 255) + wr * 64;

  if (z == 2) {
    // vT[(bh*64+d)*256 + t], 4 consecutive t -> 8B store (as round 2/3)
#pragma unroll
    for (int nj = 0; nj < 4; ++nj) {
      const int d = nj * 16 + c;
#pragma unroll
      for (int mi = 0; mi < 4; ++mi) {
        const int t0 = trow0 + mi * 16 + 4 * g;
        ushort4 pk;
        pk.x = f2bf(acc[mi][nj][0]); pk.y = f2bf(acc[mi][nj][1]);
        pk.z = f2bf(acc[mi][nj][2]); pk.w = f2bf(acc[mi][nj][3]);
        *reinterpret_cast<ushort4*>(
            vT_ws + (((size_t)b * NH + h) * HS + d) * T_SEQ + t0) = pk;
      }
    }
  } else {
    // q/k: stage wave's 64x64 bf16 tile in LDS (chunk-swizzled), then
    // read back conflict-free as 16B chunks -> coalesced dwordx4 stores.
    unsigned short* dstb = (z == 0) ? q_ws : k_ws;
    char* OS = (char*)XA + w * 8192;   // per-wave 8 KB region
#pragma unroll
    for (int nj = 0; nj < 4; ++nj)
#pragma unroll
      for (int mi = 0; mi < 4; ++mi)
#pragma unroll
        for (int i = 0; i < 4; ++i) {
          const int r = mi * 16 + 4 * g + i;           // row in tile
          const int chk = (nj * 2 + (c >> 3)) ^ (r & 7);
          *reinterpret_cast<unsigned short*>(
              OS + r * 128 + (chk << 4) + (c & 7) * 2) = f2bf(acc[mi][nj][i]);
        }
    __syncthreads();   // waves at same point (z uniform); orders LDS ops
    unsigned short* gdst = dstb + (((size_t)b * NH + h) * T_SEQ + trow0) * HS;
#pragma unroll
    for (int p = 0; p < 8; ++p) {
      const int r = p * 8 + (l >> 3);
      const int chk = (l & 7) ^ (r & 7);
      uint4 v = *reinterpret_cast<const uint4*>(OS + r * 128 + (chk << 4));
      *reinterpret_cast<uint4*>((char*)gdst + r * 128 + (l & 7) * 16) = v;
    }
  }
#undef STAGE_QKV
}

// ---------------------------------------------------------------------------
// 3) attention (unchanged from round 3 — passed).
// ---------------------------------------------------------------------------
template<int NT>
__device__ __forceinline__ void attn_tile(
    const unsigned short* __restrict__ qg,
    const unsigned short* KL, const unsigned short* VL,
    unsigned short* __restrict__ o_ws, int bh, int qt, int g, int c)
{
  const int q0 = qt * 16;
  const int kxor = (c & 7) << 4;

  const char* qrow = (const char*)qg + (size_t)(q0 + c) * 128;
  const bf16x8 qb0 = *reinterpret_cast<const bf16x8*>(qrow + g * 16);
  const bf16x8 qb1 = *reinterpret_cast<const bf16x8*>(qrow + 64 + g * 16);

  f32x4 s[NT];
#pragma unroll
  for (int kt = 0; kt < NT; ++kt) {
    const char* krow = (const char*)KL + (kt * 16 + c) * 128;
    bf16x8 ka0 = *reinterpret_cast<const bf16x8*>(krow + ((g * 16) ^ kxor));
    bf16x8 ka1 = *reinterpret_cast<const bf16x8*>(krow + ((64 + g * 16) ^ kxor));
    f32x4 z = {0.f, 0.f, 0.f, 0.f};
    z = __builtin_amdgcn_mfma_f32_16x16x32_bf16(ka0, qb0, z, 0, 0, 0);
    z = __builtin_amdgcn_mfma_f32_16x16x32_bf16(ka1, qb1, z, 0, 0, 0);
    s[kt] = z;
  }

  const float sc = 0.07362372251839260f;  // 384^-0.5 * log2(e)
  float mx = -1e30f;
#pragma unroll
  for (int kt = 0; kt < NT; ++kt)
#pragma unroll
    for (int i = 0; i < 4; ++i) {
      const int k = kt * 16 + 4 * g + i;
      float v = (k <= q0 + c) ? s[kt][i] * sc : -1e30f;
      s[kt][i] = v;
      mx = fmaxf(mx, v);
    }
  mx = fmaxf(mx, __shfl_xor(mx, 16));
  mx = fmaxf(mx, __shfl_xor(mx, 32));

  float sum = 0.f;
#pragma unroll
  for (int kt = 0; kt < NT; ++kt)
#pragma unroll
    for (int i = 0; i < 4; ++i) {
      float p = __builtin_exp2f(s[kt][i] - mx);
      s[kt][i] = p;
      sum += p;
    }
  sum += __shfl_xor(sum, 16);
  sum += __shfl_xor(sum, 32);
  const float inv = 1.0f / sum;

  unsigned pk0[NT], pk1[NT];
#pragma unroll
  for (int kt = 0; kt < NT; ++kt) {
    float2 p01 = {s[kt][0] * inv, s[kt][1] * inv};
    float2 p23 = {s[kt][2] * inv, s[kt][3] * inv};
    __hip_bfloat162 b01 = __float22bfloat162_rn(p01);
    __hip_bfloat162 b23 = __float22bfloat162_rn(p23);
    pk0[kt] = *reinterpret_cast<unsigned*>(&b01);
    pk1[kt] = *reinterpret_cast<unsigned*>(&b23);
  }

  f32x4 acc[4];
#pragma unroll
  for (int nt = 0; nt < 4; ++nt) { f32x4 zz = {0.f,0.f,0.f,0.f}; acc[nt] = zz; }

  const int srcA = ((g & 1) << 5) + c;
  const int srcB = srcA + 16;
  const bool hi = (g >= 2);
#pragma unroll
  for (int ks = 0; ks < NT / 2; ++ks) {
    unsigned a0A = __shfl(pk0[2 * ks],     srcA);
    unsigned a1A = __shfl(pk1[2 * ks],     srcA);
    unsigned a0B = __shfl(pk0[2 * ks],     srcB);
    unsigned a1B = __shfl(pk1[2 * ks],     srcB);
    unsigned b0A = __shfl(pk0[2 * ks + 1], srcA);
    unsigned b1A = __shfl(pk1[2 * ks + 1], srcA);
    unsigned b0B = __shfl(pk0[2 * ks + 1], srcB);
    unsigned b1B = __shfl(pk1[2 * ks + 1], srcB);
    union { unsigned u[4]; bf16x8 v; } pa;
    pa.u[0] = hi ? b0A : a0A;
    pa.u[1] = hi ? b1A : a1A;
    pa.u[2] = hi ? b0B : a0B;
    pa.u[3] = hi ? b1B : a1B;
#pragma unroll
    for (int nt = 0; nt < 4; ++nt) {
      const char* vrow = (const char*)VL + (nt * 16 + c) * 512;
      bf16x8 vb = *reinterpret_cast<const bf16x8*>(
          vrow + ((ks * 64 + g * 16) ^ kxor));
      acc[nt] = __builtin_amdgcn_mfma_f32_16x16x32_bf16(pa.v, vb, acc[nt], 0, 0, 0);
    }
  }

  const int b = bh / NH, h = bh % NH;
  unsigned short* ob = o_ws + ((size_t)(b * T_SEQ + q0)) * CIN + h * HS;
#pragma unroll
  for (int nt = 0; nt < 4; ++nt)
#pragma unroll
    for (int i = 0; i < 4; ++i)
      ob[(size_t)(4 * g + i) * CIN + nt * 16 + c] = f2bf(acc[nt][i]);
}

__global__ __launch_bounds__(512, 4) void attn_kernel(
    const unsigned short* __restrict__ q_ws,
    const unsigned short* __restrict__ k_ws,
    const unsigned short* __restrict__ vT_ws,
    unsigned short* __restrict__ o_ws)
{
  __shared__ __align__(16) unsigned short KL[256 * 64];
  __shared__ __align__(16) unsigned short VL[64 * 256];

  const int tid = threadIdx.x;
  const int w = tid >> 6, l = tid & 63, g = l >> 4, c = l & 15;
  const int bh = blockIdx.x;

  const char* kg = (const char*)(k_ws + (size_t)bh * T_SEQ * HS);
  const char* vg = (const char*)(vT_ws + (size_t)bh * HS * T_SEQ);
#pragma unroll
  for (int i = 0; i < 4; ++i) {
    const int cid = i * 512 + w * 64 + l;
    const int rk = cid >> 3, pk_ = cid & 7;
    gl_lds16(kg + rk * 128 + ((pk_ ^ (rk & 7)) << 4),
             (char*)KL + (size_t)(i * 512 + w * 64) * 16);
    const int rv = cid >> 5, pv = cid & 31;
    const int sv = (pv & ~7) | ((pv & 7) ^ (rv & 7));
    gl_lds16(vg + rv * 512 + (sv << 4),
             (char*)VL + (size_t)(i * 512 + w * 64) * 16);
  }
  __syncthreads();

  const unsigned short* qg = q_ws + (size_t)bh * T_SEQ * HS;
  switch (w) {
    case 0: attn_tile<2>(qg, KL, VL, o_ws, bh, 0, g, c);
            attn_tile<16>(qg, KL, VL, o_ws, bh, 15, g, c); break;
    case 1: attn_tile<2>(qg, KL, VL, o_ws, bh, 1, g, c);
            attn_tile<16>(qg, KL, VL, o_ws, bh, 14, g, c); break;
    case 2: attn_tile<4>(qg, KL, VL, o_ws, bh, 2, g, c);
            attn_tile<14>(qg, KL, VL, o_ws, bh, 13, g, c); break;
    case 3: attn_tile<4>(qg, KL, VL, o_ws, bh, 3, g, c);
            attn_tile<14>(qg, KL, VL, o_ws, bh, 12, g, c); break;
    case 4: attn_tile<6>(qg, KL, VL, o_ws, bh, 4, g, c);
            attn_tile<12>(qg, KL, VL, o_ws, bh, 11, g, c); break;
    case 5: attn_tile<6>(qg, KL, VL, o_ws, bh, 5, g, c);
            attn_tile<12>(qg, KL, VL, o_ws, bh, 10, g, c); break;
    case 6: attn_tile<8>(qg, KL, VL, o_ws, bh, 6, g, c);
            attn_tile<10>(qg, KL, VL, o_ws, bh, 9, g, c); break;
    case 7: attn_tile<8>(qg, KL, VL, o_ws, bh, 7, g, c);
            attn_tile<10>(qg, KL, VL, o_ws, bh, 8, g, c); break;
  }
}

// ---------------------------------------------------------------------------
// 5) output projection: dbuf + swizzle core, direct f32 stores.
// ---------------------------------------------------------------------------
__global__ __launch_bounds__(256) void proj_kernel(
    const unsigned short* __restrict__ ob,
    const unsigned short* __restrict__ wpt,
    const float* __restrict__ bp,
    float* __restrict__ out)
{
  __shared__ __align__(16) unsigned short XA[2][128][64];
  __shared__ __align__(16) unsigned short XB[2][128][64];

  const int tid = threadIdx.x;
  const int w = tid >> 6, l = tid & 63, g = l >> 4, c = l & 15;
  const int wr = w >> 1, wc = w & 1;

  const int wid = ((int)blockIdx.x & 7) * 96 + ((int)blockIdx.x >> 3);
  const int n_t = wid % 3, m_t = wid / 3;
  const int m0 = m_t * 128, n0 = n_t * 128;

  f32x4 acc[4][4];
#pragma unroll
  for (int mi = 0; mi < 4; ++mi)
#pragma unroll
    for (int nj = 0; nj < 4; ++nj) { f32x4 zz = {0.f,0.f,0.f,0.f}; acc[mi][nj] = zz; }

  const int lrow = l >> 3;
  const int lchk = (l & 7) ^ lrow;
  const char* ga = (const char*)ob +
      ((size_t)(m0 + w * 32 + lrow) * CIN + lchk * 8) * 2;
  const char* gb = (const char*)wpt +
      ((size_t)(n0 + w * 32 + lrow) * CIN + lchk * 8) * 2;

#define STAGE_PRJ(buf, k0)                                              \
  {                                                                     \
    _Pragma("unroll")                                                   \
    for (int i_ = 0; i_ < 4; ++i_) {                                    \
      gl_lds16(ga + ((k0) + i_ * 8 * CIN) * 2, &XA[buf][w * 32 + i_ * 8][0]); \
      gl_lds16(gb + ((k0) + i_ * 8 * CIN) * 2, &XB[buf][w * 32 + i_ * 8][0]); \
    }                                                                   \
  }

  STAGE_PRJ(0, 0);
  __syncthreads();

  int cur = 0;
  for (int t = 0; t < 6; ++t) {
    if (t < 5) STAGE_PRJ(cur ^ 1, (t + 1) * 64);
#pragma unroll
    for (int kk = 0; kk < 2; ++kk) {
      bf16x8 a[4], b[4];
#pragma unroll
      for (int mi = 0; mi < 4; ++mi) {
        const int row = wr * 64 + mi * 16 + c;
        a[mi] = *reinterpret_cast<const bf16x8*>(
            (const char*)&XA[cur][row][0] + (((kk * 4 + g) ^ (c & 7)) << 4));
      }
#pragma unroll
      for (int nj = 0; nj < 4; ++nj) {
        const int row = wc * 64 + nj * 16 + c;
        b[nj] = *reinterpret_cast<const bf16x8*>(
            (const char*)&XB[cur][row][0] + (((kk * 4 + g) ^ (c & 7)) << 4));
      }
#pragma unroll
      for (int mi = 0; mi < 4; ++mi)
#pragma unroll
        for (int nj = 0; nj < 4; ++nj)
          acc[mi][nj] = __builtin_amdgcn_mfma_f32_16x16x32_bf16(
              a[mi], b[nj], acc[mi][nj], 0, 0, 0);
    }
    __syncthreads();
    cur ^= 1;
  }

#pragma unroll
  for (int nj = 0; nj < 4; ++nj) {
    const int col = n0 + wc * 64 + nj * 16 + c;
    const float bias = bp[col];
#pragma unroll
    for (int mi = 0; mi < 4; ++mi) {
      const int mrow = m0 + wr * 64 + mi * 16 + 4 * g;
#pragma unroll
      for (int i = 0; i < 4; ++i)
        out[(size_t)(mrow + i) * CIN + col] = acc[mi][nj][i] + bias;
    }
  }
#undef STAGE_PRJ
}

// ---------------------------------------------------------------------------
extern "C" void kernel_launch(void* const* d_in, const int* in_sizes, int n_in,
                              void* d_out, int out_size, void* d_ws, size_t ws_size,
                              hipStream_t stream)
{
  // setup_inputs order: x, Wk, Wq, Wv, Wp, bp
  const float* x  = (const float*)d_in[0];
  const float* Wk = (const float*)d_in[1];
  const float* Wq = (const float*)d_in[2];
  const float* Wv = (const float*)d_in[3];
  const float* Wp = (const float*)d_in[4];
  const float* bp = (const float*)d_in[5];
  float* out = (float*)d_out;

  unsigned short* ws    = (unsigned short*)d_ws;
  unsigned short* xb_o  = ws;              // x_bf16; aliased as o after qkv
  unsigned short* q_ws  = ws + ELEMS;      // q; aliased as WpT after attn
  unsigned short* k_ws  = ws + 2 * ELEMS;
  unsigned short* vT_ws = ws + 3 * ELEMS;
  unsigned short* wqkvT = (unsigned short*)d_out;  // pre-proj scratch

  convert_x   <<<6144, 256, 0, stream>>>(x, xb_o);
  convert_wqkv<<<dim3(12, 12, 3), 256, 0, stream>>>(Wq, Wk, Wv, wqkvT);
  gemm_qkv    <<<2304, 256, 0, stream>>>(xb_o, wqkvT, q_ws, k_ws, vT_ws);
  attn_kernel <<<BATCH * NH, 512, 0, stream>>>(q_ws, k_ws, vT_ws, xb_o);
  transpose_w <<<dim3(12, 12), 256, 0, stream>>>(Wp, q_ws);
  proj_kernel <<<768, 256, 0, stream>>>(xb_o, q_ws, bp, out);
}

// Round 5
// 115.807 us; speedup vs baseline: 2.6669x; 1.0353x over previous
//
#include <hip/hip_runtime.h>
#include <hip/hip_bf16.h>

// MultiHeadAttention forward, MI355X gfx950.  B=128,T=256,C=384,H=6,hs=64.
//
// Pipeline:
//   0) convert_x    : x f32 -> bf16                       (buf0)
//   1) convert_wqkv : Wq|Wk|Wv f32 -> transposed bf16 [1152][384] (d_out scratch)
//   2) gemm_qkv     : fused QKV GEMM 32768x1152, 128x128 tile, single-buffer
//                     32KB LDS + XOR-swizzle (4 blocks/CU), coalesced epilogue
//   3) attn_kernel  : 1 block/bh, 8 waves; K+Vt in swizzled LDS; swapped QK^T;
//                     s_setprio around MFMA clusters
//   4) transpose_w  : Wp -> bf16 [384][384] into q region (q dead)
//   5) proj         : out = o @ Wp + bp (f32), single-buffer swizzled GEMM
//
// ws usage: exactly 4 * 32768*384 * 2B = 100,663,296 bytes.

#define T_SEQ 256
#define NH 6
#define HS 64
#define CIN 384
#define BATCH 128
#define BT (BATCH * T_SEQ)            // 32768
#define ELEMS ((size_t)BT * CIN)      // 12,582,912 per buffer

using f32x4  = __attribute__((ext_vector_type(4))) float;
using bf16x8 = __attribute__((ext_vector_type(8))) short;  // 8 bf16 in 4 VGPRs

typedef __attribute__((address_space(3))) void       lds_vp;
typedef __attribute__((address_space(1))) const void glob_vp;

// f32 -> bf16 round-to-nearest-even
static __device__ __forceinline__ unsigned short f2bf(float f) {
  union { float f; unsigned u; } v; v.f = f;
  unsigned r = v.u + 0x7FFFu + ((v.u >> 16) & 1u);
  return (unsigned short)(r >> 16);
}

static __device__ __forceinline__ bf16x8 ld_bf8(const unsigned short* p) {
  return *reinterpret_cast<const bf16x8*>(p);
}

static __device__ __forceinline__ void gl_lds16(const void* g, void* l) {
  __builtin_amdgcn_global_load_lds((glob_vp*)g, (lds_vp*)l, 16, 0, 0);
}

// ---------------------------------------------------------------------------
// 0) x f32 -> bf16.
// ---------------------------------------------------------------------------
__global__ __launch_bounds__(256) void convert_x(
    const float* __restrict__ x, unsigned short* __restrict__ xb)
{
  size_t i = (((size_t)blockIdx.x << 8) + threadIdx.x) << 3;
  float4 f0 = *reinterpret_cast<const float4*>(x + i);
  float4 f1 = *reinterpret_cast<const float4*>(x + i + 4);
  uint4 pk;
  pk.x = f2bf(f0.x) | ((unsigned)f2bf(f0.y) << 16);
  pk.y = f2bf(f0.z) | ((unsigned)f2bf(f0.w) << 16);
  pk.z = f2bf(f1.x) | ((unsigned)f2bf(f1.y) << 16);
  pk.w = f2bf(f1.z) | ((unsigned)f2bf(f1.w) << 16);
  *reinterpret_cast<uint4*>(xb + i) = pk;
}

// ---------------------------------------------------------------------------
// 1) Wq/Wk/Wv f32 [384][384] -> bf16 transposed [z*384 + n][k].  grid(12,12,3).
// ---------------------------------------------------------------------------
__global__ __launch_bounds__(256) void convert_wqkv(
    const float* __restrict__ Wq, const float* __restrict__ Wk,
    const float* __restrict__ Wv, unsigned short* __restrict__ dst)
{
  __shared__ float t[32][33];
  const int z = blockIdx.z;
  const float* __restrict__ W = (z == 0) ? Wq : (z == 1) ? Wk : Wv;
  const int tx = threadIdx.x & 31, ty = threadIdx.x >> 5;
  const int k0 = blockIdx.x * 32, n0 = blockIdx.y * 32;
#pragma unroll
  for (int i = 0; i < 4; ++i)
    t[ty + 8 * i][tx] = W[(size_t)(k0 + ty + 8 * i) * CIN + n0 + tx];
  __syncthreads();
#pragma unroll
  for (int i = 0; i < 4; ++i)
    dst[((size_t)z * CIN + n0 + ty + 8 * i) * CIN + k0 + tx] =
        f2bf(t[tx][ty + 8 * i]);
}

// 4) Wp -> bf16 transposed [n][k].  grid(12,12).
__global__ __launch_bounds__(256) void transpose_w(
    const float* __restrict__ W, unsigned short* __restrict__ dst)
{
  __shared__ float t[32][33];
  const int tx = threadIdx.x & 31, ty = threadIdx.x >> 5;
  const int k0 = blockIdx.x * 32, n0 = blockIdx.y * 32;
#pragma unroll
  for (int i = 0; i < 4; ++i)
    t[ty + 8 * i][tx] = W[(size_t)(k0 + ty + 8 * i) * CIN + n0 + tx];
  __syncthreads();
#pragma unroll
  for (int i = 0; i < 4; ++i)
    dst[((size_t)(n0 + ty + 8 * i)) * CIN + k0 + tx] = f2bf(t[tx][ty + 8 * i]);
}

// ---------------------------------------------------------------------------
// 2) Fused QKV GEMM, single-buffered + swizzled (32 KB LDS -> 4 blocks/CU).
// LDS: SM[0]=A-tile, SM[1]=B-tile, each [128 rows][64 k], row = 8 chunks of
// 16 B.  Swizzle involution: LDS[r][chunk p] holds global chunk p ^ (r&7);
// staging pre-swizzles the GLOBAL source address (linear LDS dest); fragment
// reads XOR the chunk index with (row&7) -> 0 bank conflicts.
// ---------------------------------------------------------------------------
__global__ __launch_bounds__(256) void gemm_qkv(
    const unsigned short* __restrict__ xb,
    const unsigned short* __restrict__ wt,
    unsigned short* __restrict__ q_ws, unsigned short* __restrict__ k_ws,
    unsigned short* __restrict__ vT_ws)
{
  __shared__ __align__(16) unsigned short SM[2][128][64];  // 32 KB total

  const int tid = threadIdx.x;
  const int w = tid >> 6, l = tid & 63, g = l >> 4, c = l & 15;
  const int wr = w >> 1, wc = w & 1;

  const int wid = ((int)blockIdx.x & 7) * 288 + ((int)blockIdx.x >> 3);
  const int n_t = wid % 9, m_t = wid / 9;
  const int m0 = m_t * 128, n0 = n_t * 128;

  f32x4 acc[4][4];
#pragma unroll
  for (int mi = 0; mi < 4; ++mi)
#pragma unroll
    for (int nj = 0; nj < 4; ++nj) { f32x4 zz = {0.f,0.f,0.f,0.f}; acc[mi][nj] = zz; }

  const int lrow = l >> 3;               // 0..7 (row within 8-row group)
  const int lchk = (l & 7) ^ lrow;       // pre-swizzled source chunk
  const char* ga = (const char*)xb +
      ((size_t)(m0 + w * 32 + lrow) * CIN + lchk * 8) * 2;
  const char* gb = (const char*)wt +
      ((size_t)(n0 + w * 32 + lrow) * CIN + lchk * 8) * 2;

  for (int t = 0; t < 6; ++t) {
#pragma unroll
    for (int i_ = 0; i_ < 4; ++i_) {
      gl_lds16(ga + (t * 64 + i_ * 8 * CIN) * 2, &SM[0][w * 32 + i_ * 8][0]);
      gl_lds16(gb + (t * 64 + i_ * 8 * CIN) * 2, &SM[1][w * 32 + i_ * 8][0]);
    }
    __syncthreads();
#pragma unroll
    for (int kk = 0; kk < 2; ++kk) {
      bf16x8 a[4], b[4];
#pragma unroll
      for (int mi = 0; mi < 4; ++mi) {
        const int row = wr * 64 + mi * 16 + c;
        a[mi] = *reinterpret_cast<const bf16x8*>(
            (const char*)&SM[0][row][0] + (((kk * 4 + g) ^ (c & 7)) << 4));
      }
#pragma unroll
      for (int nj = 0; nj < 4; ++nj) {
        const int row = wc * 64 + nj * 16 + c;
        b[nj] = *reinterpret_cast<const bf16x8*>(
            (const char*)&SM[1][row][0] + (((kk * 4 + g) ^ (c & 7)) << 4));
      }
      __builtin_amdgcn_s_setprio(1);
#pragma unroll
      for (int mi = 0; mi < 4; ++mi)
#pragma unroll
        for (int nj = 0; nj < 4; ++nj)
          acc[mi][nj] = __builtin_amdgcn_mfma_f32_16x16x32_bf16(
              a[mi], b[nj], acc[mi][nj], 0, 0, 0);
      __builtin_amdgcn_s_setprio(0);
    }
    __syncthreads();
  }

  // Epilogue. Wave's 64 cols = exactly one head (colw 64-aligned).
  const int z = n_t / 3;
  const int colw = (n_t % 3) * 128 + wc * 64;
  const int h = colw >> 6;
  const int b = m0 >> 8;
  const int trow0 = (m0 & 255) + wr * 64;

  if (z == 2) {
    // vT[(bh*64+d)*256 + t], 4 consecutive t -> 8B store
#pragma unroll
    for (int nj = 0; nj < 4; ++nj) {
      const int d = nj * 16 + c;
#pragma unroll
      for (int mi = 0; mi < 4; ++mi) {
        const int t0 = trow0 + mi * 16 + 4 * g;
        ushort4 pk;
        pk.x = f2bf(acc[mi][nj][0]); pk.y = f2bf(acc[mi][nj][1]);
        pk.z = f2bf(acc[mi][nj][2]); pk.w = f2bf(acc[mi][nj][3]);
        *reinterpret_cast<ushort4*>(
            vT_ws + (((size_t)b * NH + h) * HS + d) * T_SEQ + t0) = pk;
      }
    }
  } else {
    // q/k: bounce wave's 64x64 tile through LDS (chunk-swizzled), then
    // conflict-free 16B reads -> coalesced dwordx4 stores.
    unsigned short* dstb = (z == 0) ? q_ws : k_ws;
    char* OS = (char*)SM + w * 8192;   // per-wave 8 KB region
#pragma unroll
    for (int nj = 0; nj < 4; ++nj)
#pragma unroll
      for (int mi = 0; mi < 4; ++mi)
#pragma unroll
        for (int i = 0; i < 4; ++i) {
          const int r = mi * 16 + 4 * g + i;           // row in tile
          const int chk = (nj * 2 + (c >> 3)) ^ (r & 7);
          *reinterpret_cast<unsigned short*>(
              OS + r * 128 + (chk << 4) + (c & 7) * 2) = f2bf(acc[mi][nj][i]);
        }
    __syncthreads();   // z is block-uniform; orders LDS ops
    unsigned short* gdst = dstb + (((size_t)b * NH + h) * T_SEQ + trow0) * HS;
#pragma unroll
    for (int p = 0; p < 8; ++p) {
      const int r = p * 8 + (l >> 3);
      const int chk = (l & 7) ^ (r & 7);
      uint4 v = *reinterpret_cast<const uint4*>(OS + r * 128 + (chk << 4));
      *reinterpret_cast<uint4*>((char*)gdst + r * 128 + (l & 7) * 16) = v;
    }
  }
}

// ---------------------------------------------------------------------------
// 3) attention: 1 block/bh, 8 waves; K,Vt in swizzled LDS; swapped QK^T;
// in-register softmax; shfl-built PV A-frags; setprio around MFMA clusters.
// ---------------------------------------------------------------------------
template<int NT>
__device__ __forceinline__ void attn_tile(
    const unsigned short* __restrict__ qg,
    const unsigned short* KL, const unsigned short* VL,
    unsigned short* __restrict__ o_ws, int bh, int qt, int g, int c)
{
  const int q0 = qt * 16;
  const int kxor = (c & 7) << 4;

  const char* qrow = (const char*)qg + (size_t)(q0 + c) * 128;
  const bf16x8 qb0 = *reinterpret_cast<const bf16x8*>(qrow + g * 16);
  const bf16x8 qb1 = *reinterpret_cast<const bf16x8*>(qrow + 64 + g * 16);

  f32x4 s[NT];
#pragma unroll
  for (int kt = 0; kt < NT; ++kt) {
    const char* krow = (const char*)KL + (kt * 16 + c) * 128;
    bf16x8 ka0 = *reinterpret_cast<const bf16x8*>(krow + ((g * 16) ^ kxor));
    bf16x8 ka1 = *reinterpret_cast<const bf16x8*>(krow + ((64 + g * 16) ^ kxor));
    f32x4 z = {0.f, 0.f, 0.f, 0.f};
    __builtin_amdgcn_s_setprio(1);
    z = __builtin_amdgcn_mfma_f32_16x16x32_bf16(ka0, qb0, z, 0, 0, 0);
    z = __builtin_amdgcn_mfma_f32_16x16x32_bf16(ka1, qb1, z, 0, 0, 0);
    __builtin_amdgcn_s_setprio(0);
    s[kt] = z;
  }

  const float sc = 0.07362372251839260f;  // 384^-0.5 * log2(e)
  float mx = -1e30f;
#pragma unroll
  for (int kt = 0; kt < NT; ++kt)
#pragma unroll
    for (int i = 0; i < 4; ++i) {
      const int k = kt * 16 + 4 * g + i;
      float v = (k <= q0 + c) ? s[kt][i] * sc : -1e30f;
      s[kt][i] = v;
      mx = fmaxf(mx, v);
    }
  mx = fmaxf(mx, __shfl_xor(mx, 16));
  mx = fmaxf(mx, __shfl_xor(mx, 32));

  float sum = 0.f;
#pragma unroll
  for (int kt = 0; kt < NT; ++kt)
#pragma unroll
    for (int i = 0; i < 4; ++i) {
      float p = __builtin_exp2f(s[kt][i] - mx);
      s[kt][i] = p;
      sum += p;
    }
  sum += __shfl_xor(sum, 16);
  sum += __shfl_xor(sum, 32);
  const float inv = 1.0f / sum;

  unsigned pk0[NT], pk1[NT];
#pragma unroll
  for (int kt = 0; kt < NT; ++kt) {
    float2 p01 = {s[kt][0] * inv, s[kt][1] * inv};
    float2 p23 = {s[kt][2] * inv, s[kt][3] * inv};
    __hip_bfloat162 b01 = __float22bfloat162_rn(p01);
    __hip_bfloat162 b23 = __float22bfloat162_rn(p23);
    pk0[kt] = *reinterpret_cast<unsigned*>(&b01);
    pk1[kt] = *reinterpret_cast<unsigned*>(&b23);
  }

  f32x4 acc[4];
#pragma unroll
  for (int nt = 0; nt < 4; ++nt) { f32x4 zz = {0.f,0.f,0.f,0.f}; acc[nt] = zz; }

  const int srcA = ((g & 1) << 5) + c;
  const int srcB = srcA + 16;
  const bool hi = (g >= 2);
#pragma unroll
  for (int ks = 0; ks < NT / 2; ++ks) {
    unsigned a0A = __shfl(pk0[2 * ks],     srcA);
    unsigned a1A = __shfl(pk1[2 * ks],     srcA);
    unsigned a0B = __shfl(pk0[2 * ks],     srcB);
    unsigned a1B = __shfl(pk1[2 * ks],     srcB);
    unsigned b0A = __shfl(pk0[2 * ks + 1], srcA);
    unsigned b1A = __shfl(pk1[2 * ks + 1], srcA);
    unsigned b0B = __shfl(pk0[2 * ks + 1], srcB);
    unsigned b1B = __shfl(pk1[2 * ks + 1], srcB);
    union { unsigned u[4]; bf16x8 v; } pa;
    pa.u[0] = hi ? b0A : a0A;
    pa.u[1] = hi ? b1A : a1A;
    pa.u[2] = hi ? b0B : a0B;
    pa.u[3] = hi ? b1B : a1B;
    __builtin_amdgcn_s_setprio(1);
#pragma unroll
    for (int nt = 0; nt < 4; ++nt) {
      const char* vrow = (const char*)VL + (nt * 16 + c) * 512;
      bf16x8 vb = *reinterpret_cast<const bf16x8*>(
          vrow + ((ks * 64 + g * 16) ^ kxor));
      acc[nt] = __builtin_amdgcn_mfma_f32_16x16x32_bf16(pa.v, vb, acc[nt], 0, 0, 0);
    }
    __builtin_amdgcn_s_setprio(0);
  }

  const int b = bh / NH, h = bh % NH;
  unsigned short* ob = o_ws + ((size_t)(b * T_SEQ + q0)) * CIN + h * HS;
#pragma unroll
  for (int nt = 0; nt < 4; ++nt)
#pragma unroll
    for (int i = 0; i < 4; ++i)
      ob[(size_t)(4 * g + i) * CIN + nt * 16 + c] = f2bf(acc[nt][i]);
}

__global__ __launch_bounds__(512, 4) void attn_kernel(
    const unsigned short* __restrict__ q_ws,
    const unsigned short* __restrict__ k_ws,
    const unsigned short* __restrict__ vT_ws,
    unsigned short* __restrict__ o_ws)
{
  __shared__ __align__(16) unsigned short KL[256 * 64];
  __shared__ __align__(16) unsigned short VL[64 * 256];

  const int tid = threadIdx.x;
  const int w = tid >> 6, l = tid & 63, g = l >> 4, c = l & 15;
  const int bh = blockIdx.x;

  const char* kg = (const char*)(k_ws + (size_t)bh * T_SEQ * HS);
  const char* vg = (const char*)(vT_ws + (size_t)bh * HS * T_SEQ);
#pragma unroll
  for (int i = 0; i < 4; ++i) {
    const int cid = i * 512 + w * 64 + l;
    const int rk = cid >> 3, pk_ = cid & 7;
    gl_lds16(kg + rk * 128 + ((pk_ ^ (rk & 7)) << 4),
             (char*)KL + (size_t)(i * 512 + w * 64) * 16);
    const int rv = cid >> 5, pv = cid & 31;
    const int sv = (pv & ~7) | ((pv & 7) ^ (rv & 7));
    gl_lds16(vg + rv * 512 + (sv << 4),
             (char*)VL + (size_t)(i * 512 + w * 64) * 16);
  }
  __syncthreads();

  const unsigned short* qg = q_ws + (size_t)bh * T_SEQ * HS;
  switch (w) {
    case 0: attn_tile<2>(qg, KL, VL, o_ws, bh, 0, g, c);
            attn_tile<16>(qg, KL, VL, o_ws, bh, 15, g, c); break;
    case 1: attn_tile<2>(qg, KL, VL, o_ws, bh, 1, g, c);
            attn_tile<16>(qg, KL, VL, o_ws, bh, 14, g, c); break;
    case 2: attn_tile<4>(qg, KL, VL, o_ws, bh, 2, g, c);
            attn_tile<14>(qg, KL, VL, o_ws, bh, 13, g, c); break;
    case 3: attn_tile<4>(qg, KL, VL, o_ws, bh, 3, g, c);
            attn_tile<14>(qg, KL, VL, o_ws, bh, 12, g, c); break;
    case 4: attn_tile<6>(qg, KL, VL, o_ws, bh, 4, g, c);
            attn_tile<12>(qg, KL, VL, o_ws, bh, 11, g, c); break;
    case 5: attn_tile<6>(qg, KL, VL, o_ws, bh, 5, g, c);
            attn_tile<12>(qg, KL, VL, o_ws, bh, 10, g, c); break;
    case 6: attn_tile<8>(qg, KL, VL, o_ws, bh, 6, g, c);
            attn_tile<10>(qg, KL, VL, o_ws, bh, 9, g, c); break;
    case 7: attn_tile<8>(qg, KL, VL, o_ws, bh, 7, g, c);
            attn_tile<10>(qg, KL, VL, o_ws, bh, 8, g, c); break;
  }
}

// ---------------------------------------------------------------------------
// 5) output projection: single-buffer swizzled core, direct f32 stores.
// ---------------------------------------------------------------------------
__global__ __launch_bounds__(256) void proj_kernel(
    const unsigned short* __restrict__ ob,
    const unsigned short* __restrict__ wpt,
    const float* __restrict__ bp,
    float* __restrict__ out)
{
  __shared__ __align__(16) unsigned short SM[2][128][64];

  const int tid = threadIdx.x;
  const int w = tid >> 6, l = tid & 63, g = l >> 4, c = l & 15;
  const int wr = w >> 1, wc = w & 1;

  const int wid = ((int)blockIdx.x & 7) * 96 + ((int)blockIdx.x >> 3);
  const int n_t = wid % 3, m_t = wid / 3;
  const int m0 = m_t * 128, n0 = n_t * 128;

  f32x4 acc[4][4];
#pragma unroll
  for (int mi = 0; mi < 4; ++mi)
#pragma unroll
    for (int nj = 0; nj < 4; ++nj) { f32x4 zz = {0.f,0.f,0.f,0.f}; acc[mi][nj] = zz; }

  const int lrow = l >> 3;
  const int lchk = (l & 7) ^ lrow;
  const char* ga = (const char*)ob +
      ((size_t)(m0 + w * 32 + lrow) * CIN + lchk * 8) * 2;
  const char* gb = (const char*)wpt +
      ((size_t)(n0 + w * 32 + lrow) * CIN + lchk * 8) * 2;

  for (int t = 0; t < 6; ++t) {
#pragma unroll
    for (int i_ = 0; i_ < 4; ++i_) {
      gl_lds16(ga + (t * 64 + i_ * 8 * CIN) * 2, &SM[0][w * 32 + i_ * 8][0]);
      gl_lds16(gb + (t * 64 + i_ * 8 * CIN) * 2, &SM[1][w * 32 + i_ * 8][0]);
    }
    __syncthreads();
#pragma unroll
    for (int kk = 0; kk < 2; ++kk) {
      bf16x8 a[4], b[4];
#pragma unroll
      for (int mi = 0; mi < 4; ++mi) {
        const int row = wr * 64 + mi * 16 + c;
        a[mi] = *reinterpret_cast<const bf16x8*>(
            (const char*)&SM[0][row][0] + (((kk * 4 + g) ^ (c & 7)) << 4));
      }
#pragma unroll
      for (int nj = 0; nj < 4; ++nj) {
        const int row = wc * 64 + nj * 16 + c;
        b[nj] = *reinterpret_cast<const bf16x8*>(
            (const char*)&SM[1][row][0] + (((kk * 4 + g) ^ (c & 7)) << 4));
      }
      __builtin_amdgcn_s_setprio(1);
#pragma unroll
      for (int mi = 0; mi < 4; ++mi)
#pragma unroll
        for (int nj = 0; nj < 4; ++nj)
          acc[mi][nj] = __builtin_amdgcn_mfma_f32_16x16x32_bf16(
              a[mi], b[nj], acc[mi][nj], 0, 0, 0);
      __builtin_amdgcn_s_setprio(0);
    }
    __syncthreads();
  }

#pragma unroll
  for (int nj = 0; nj < 4; ++nj) {
    const int col = n0 + wc * 64 + nj * 16 + c;
    const float bias = bp[col];
#pragma unroll
    for (int mi = 0; mi < 4; ++mi) {
      const int mrow = m0 + wr * 64 + mi * 16 + 4 * g;
#pragma unroll
      for (int i = 0; i < 4; ++i)
        out[(size_t)(mrow + i) * CIN + col] = acc[mi][nj][i] + bias;
    }
  }
}

// ---------------------------------------------------------------------------
extern "C" void kernel_launch(void* const* d_in, const int* in_sizes, int n_in,
                              void* d_out, int out_size, void* d_ws, size_t ws_size,
                              hipStream_t stream)
{
  // setup_inputs order: x, Wk, Wq, Wv, Wp, bp
  const float* x  = (const float*)d_in[0];
  const float* Wk = (const float*)d_in[1];
  const float* Wq = (const float*)d_in[2];
  const float* Wv = (const float*)d_in[3];
  const float* Wp = (const float*)d_in[4];
  const float* bp = (const float*)d_in[5];
  float* out = (float*)d_out;

  unsigned short* ws    = (unsigned short*)d_ws;
  unsigned short* xb_o  = ws;              // x_bf16; aliased as o after qkv
  unsigned short* q_ws  = ws + ELEMS;      // q; aliased as WpT after attn
  unsigned short* k_ws  = ws + 2 * ELEMS;
  unsigned short* vT_ws = ws + 3 * ELEMS;
  unsigned short* wqkvT = (unsigned short*)d_out;  // pre-proj scratch

  convert_x   <<<6144, 256, 0, stream>>>(x, xb_o);
  convert_wqkv<<<dim3(12, 12, 3), 256, 0, stream>>>(Wq, Wk, Wv, wqkvT);
  gemm_qkv    <<<2304, 256, 0, stream>>>(xb_o, wqkvT, q_ws, k_ws, vT_ws);
  attn_kernel <<<BATCH * NH, 512, 0, stream>>>(q_ws, k_ws, vT_ws, xb_o);
  transpose_w <<<dim3(12, 12), 256, 0, stream>>>(Wp, q_ws);
  proj_kernel <<<768, 256, 0, stream>>>(xb_o, q_ws, bp, out);
}